// Round 2
// baseline (344.899 us; speedup 1.0000x reference)
//
#include <hip/hip_runtime.h>

typedef float f32x4 __attribute__((ext_vector_type(4)));
typedef _Float16 h16x8 __attribute__((ext_vector_type(8)));
typedef _Float16 h16x4 __attribute__((ext_vector_type(4)));

#define GLOAD_LDS16(gp, lp) __builtin_amdgcn_global_load_lds(               \
    (const __attribute__((address_space(1))) void*)(gp),                    \
    (__attribute__((address_space(3))) void*)(lp), 16, 0, 0)

// ---------------------------------------------------------------------------
// cast x (f32) -> f16, 8 elems/thread
__global__ __launch_bounds__(256) void cast_x(const float* __restrict__ x,
                                              _Float16* __restrict__ xh) {
  long i = (long)blockIdx.x * 256 + threadIdx.x;  // 8-elem groups
  f32x4 a = *(const f32x4*)(x + i * 8);
  f32x4 b = *(const f32x4*)(x + i * 8 + 4);
  h16x8 h;
  h[0] = (_Float16)a[0]; h[1] = (_Float16)a[1];
  h[2] = (_Float16)a[2]; h[3] = (_Float16)a[3];
  h[4] = (_Float16)b[0]; h[5] = (_Float16)b[1];
  h[6] = (_Float16)b[2]; h[7] = (_Float16)b[3];
  *(h16x8*)(xh + i * 8) = h;
}

// ---------------------------------------------------------------------------
// transpose + cast weight: in f32 (K x N) row-major -> out f16 (N x K), *scale
__global__ __launch_bounds__(256) void tcw(const float* __restrict__ in,
                                           _Float16* __restrict__ out,
                                           int Kd, int Nd, float scale) {
  __shared__ float tile[64][65];
  const int t = threadIdx.x;
  const int k0 = blockIdx.y * 64, n0 = blockIdx.x * 64;
  const int tr = t >> 4, tc = (t & 15) * 4;
#pragma unroll
  for (int i = 0; i < 4; ++i) {
    int r = i * 16 + tr;
    f32x4 a = *(const f32x4*)(in + (long)(k0 + r) * Nd + n0 + tc);
    tile[r][tc + 0] = a[0]; tile[r][tc + 1] = a[1];
    tile[r][tc + 2] = a[2]; tile[r][tc + 3] = a[3];
  }
  __syncthreads();
#pragma unroll
  for (int i = 0; i < 4; ++i) {
    int r = i * 16 + tr;  // n index
    h16x4 h;
#pragma unroll
    for (int q = 0; q < 4; ++q) h[q] = (_Float16)(tile[tc + q][r] * scale);
    *(h16x4*)(out + (long)(n0 + r) * Kd + k0 + tc) = h;
  }
}

// ---------------------------------------------------------------------------
// f16 tile transpose: in (R x C, ld=Cd) -> out (C x R, ld=R), batched
__global__ __launch_bounds__(256) void trans16(const _Float16* __restrict__ in,
                                               _Float16* __restrict__ out,
                                               int R, int Cd, long ibatch, long obatch) {
  __shared__ _Float16 tile[64][72];
  in += (long)blockIdx.z * ibatch;
  out += (long)blockIdx.z * obatch;
  const int t = threadIdx.x;
  const int r0 = blockIdx.y * 64, c0 = blockIdx.x * 64;
  const int tr = t >> 3, tc8 = (t & 7) * 8;
#pragma unroll
  for (int i = 0; i < 2; ++i) {
    int r = i * 32 + tr;
    h16x8 a = *(const h16x8*)(in + (long)(r0 + r) * Cd + c0 + tc8);
    *(h16x8*)(&tile[r][tc8]) = a;
  }
  __syncthreads();
#pragma unroll
  for (int i = 0; i < 2; ++i) {
    int r = i * 32 + tr;  // c index
    h16x8 h;
#pragma unroll
    for (int q = 0; q < 8; ++q) h[q] = tile[tc8 + q][r];
    *(h16x8*)(out + (long)(c0 + r) * R + r0 + tc8) = h;
  }
}

// ---------------------------------------------------------------------------
// lambda_full = exp(sum lq1*lk1) - exp(sum lq2*lk2) + 0.8
__global__ __launch_bounds__(1024) void lambda_k(const float* __restrict__ lq1,
                                                 const float* __restrict__ lk1,
                                                 const float* __restrict__ lq2,
                                                 const float* __restrict__ lk2,
                                                 float* __restrict__ lam) {
  __shared__ float sh1[16], sh2[16];
  const int t = threadIdx.x;
  float p1 = lq1[t] * lk1[t];
  float p2 = lq2[t] * lk2[t];
#pragma unroll
  for (int off = 1; off < 64; off <<= 1) {
    p1 += __shfl_xor(p1, off);
    p2 += __shfl_xor(p2, off);
  }
  if ((t & 63) == 0) { sh1[t >> 6] = p1; sh2[t >> 6] = p2; }
  __syncthreads();
  if (t == 0) {
    float s1 = 0.f, s2 = 0.f;
    for (int i = 0; i < 16; ++i) { s1 += sh1[i]; s2 += sh2[i]; }
    lam[0] = __expf(s1) - __expf(s2) + 0.8f;
  }
}

// ---------------------------------------------------------------------------
// C(M x N) = A(M x K) @ B(N x K)^T. 256 x (NREP*64) tile, BK=32, 8 waves
// (2M x 4N), quad-buffered LDS, counted vmcnt (never 0 mid-loop), one
// s_barrier per K-tile, setprio around MFMA clusters, bijective XCD swizzle.
// Requires: M%256==0, N%(NREP*64)==0, K%32==0, K>=96.
template <int NREP, typename CT>
__global__ __launch_bounds__(512, 2) void gemm256(
    const _Float16* __restrict__ A, const _Float16* __restrict__ B,
    CT* __restrict__ C, int K, int lda, int ldb, int ldc,
    long abatch, long bbatch, long cbatch, int nbx, int nby) {
  __shared__ _Float16 As[4][256 * 32];
  __shared__ _Float16 Bs[4][NREP * 64 * 32];

  // bijective XCD-aware remap (m204)
  const int nwg = gridDim.x;
  const int orig = blockIdx.x;
  const int qd = nwg >> 3, rm = nwg & 7;
  const int xcd = orig & 7, sub = orig >> 3;
  const int wgid = (xcd < rm ? xcd * (qd + 1) : rm * (qd + 1) + (xcd - rm) * qd) + sub;

  const int bz = wgid / (nbx * nby);
  const int rem = wgid - bz * nbx * nby;
  const int by = rem / nbx;
  const int bx = rem - by * nbx;

  const int t = threadIdx.x;
  const int lane = t & 63, wv = t >> 6;
  const int wm = wv >> 2, wn = wv & 3;
  const int lg = lane >> 4, l15 = lane & 15;

  const _Float16* Ab = A + (long)bz * abatch + (long)(by * 256) * lda;
  const _Float16* Bb = B + (long)bz * bbatch + (long)(bx * (NREP * 64)) * ldb;

  // stage K-tile Tt into LDS buffer b (A: 1024 chunks; B: NREP*256 chunks)
  auto stage = [&](int Tt, int b) {
    const int kof = Tt * 32;
    int c = t;
    GLOAD_LDS16(Ab + (long)(c >> 2) * lda + kof + (c & 3) * 8, &As[b][c * 8]);
    c = t + 512;
    GLOAD_LDS16(Ab + (long)(c >> 2) * lda + kof + (c & 3) * 8, &As[b][c * 8]);
    c = t;
    GLOAD_LDS16(Bb + (long)(c >> 2) * ldb + kof + (c & 3) * 8, &Bs[b][c * 8]);
    if constexpr (NREP == 4) {
      c = t + 512;
      GLOAD_LDS16(Bb + (long)(c >> 2) * ldb + kof + (c & 3) * 8, &Bs[b][c * 8]);
    }
  };

  f32x4 acc[8][NREP] = {};
  const int NT = K >> 5;

  // prologue: 3 tiles in flight, wait for tile 0 only
  stage(0, 0);
  stage(1, 1);
  stage(2, 2);
  if constexpr (NREP == 4) asm volatile("s_waitcnt vmcnt(8)" ::: "memory");
  else                     asm volatile("s_waitcnt vmcnt(6)" ::: "memory");
  __builtin_amdgcn_s_barrier();

  for (int T = 0; T < NT; ++T) {
    const int b = T & 3;
    if (T + 3 < NT) stage(T + 3, (T + 3) & 3);  // lands in buf freed at end of T-1

    const _Float16* Asb = &As[b][0];
    const _Float16* Bsb = &Bs[b][0];
    h16x8 af[8], bf[NREP];
#pragma unroll
    for (int m = 0; m < 4; ++m)
      af[m] = *(const h16x8*)(Asb + (wm * 128 + m * 16 + l15) * 32 + lg * 8);
#pragma unroll
    for (int n = 0; n < NREP; ++n)
      bf[n] = *(const h16x8*)(Bsb + (wn * (NREP * 16) + n * 16 + l15) * 32 + lg * 8);
    __builtin_amdgcn_s_setprio(1);
#pragma unroll
    for (int m = 0; m < 4; ++m)
#pragma unroll
      for (int n = 0; n < NREP; ++n)
        acc[m][n] = __builtin_amdgcn_mfma_f32_16x16x32_f16(af[m], bf[n], acc[m][n], 0, 0, 0);
    __builtin_amdgcn_s_setprio(0);
#pragma unroll
    for (int m = 4; m < 8; ++m)
      af[m] = *(const h16x8*)(Asb + (wm * 128 + m * 16 + l15) * 32 + lg * 8);
    __builtin_amdgcn_s_setprio(1);
#pragma unroll
    for (int m = 4; m < 8; ++m)
#pragma unroll
      for (int n = 0; n < NREP; ++n)
        acc[m][n] = __builtin_amdgcn_mfma_f32_16x16x32_f16(af[m], bf[n], acc[m][n], 0, 0, 0);
    __builtin_amdgcn_s_setprio(0);

    // boundary: wait tile T+1 arrived; keep newer tiles in flight (never
    // drain mid-loop). Loads/tile L = 2+NREP/2... (4 for NREP4, 3 for NREP2).
    const int ahead = NT - T - 2;  // tiles issued beyond T+1
    if constexpr (NREP == 4) {
      if (ahead >= 2)      asm volatile("s_waitcnt vmcnt(8)" ::: "memory");
      else if (ahead == 1) asm volatile("s_waitcnt vmcnt(4)" ::: "memory");
      else                 asm volatile("s_waitcnt vmcnt(0)" ::: "memory");
    } else {
      if (ahead >= 2)      asm volatile("s_waitcnt vmcnt(6)" ::: "memory");
      else if (ahead == 1) asm volatile("s_waitcnt vmcnt(3)" ::: "memory");
      else                 asm volatile("s_waitcnt vmcnt(0)" ::: "memory");
    }
    __builtin_amdgcn_s_barrier();
  }

  CT* Cb = C + (long)bz * cbatch;
  const int crow0 = by * 256 + wm * 128;
  const int ccol0 = bx * (NREP * 64) + wn * (NREP * 16);
#pragma unroll
  for (int m = 0; m < 8; ++m)
#pragma unroll
    for (int n = 0; n < NREP; ++n)
#pragma unroll
      for (int j = 0; j < 4; ++j)
        Cb[(long)(crow0 + m * 16 + lg * 4 + j) * ldc + ccol0 + n * 16 + l15] =
            (CT)acc[m][n][j];
}

// ---------------------------------------------------------------------------
// one wave per row: diff = softmax(S1) - lam * softmax(S2), f16 in/out
__global__ __launch_bounds__(256) void softmax_diff(const _Float16* __restrict__ S1,
                                                    const _Float16* __restrict__ S2,
                                                    _Float16* __restrict__ D,
                                                    const float* __restrict__ lamp) {
  const long row = (long)blockIdx.x * 4 + (threadIdx.x >> 6);
  const int lane = threadIdx.x & 63;
  const float lam = *lamp;
  const _Float16* s1 = S1 + row * 2048;
  const _Float16* s2 = S2 + row * 2048;
  float v1[32], v2[32];
  float m1 = -3e38f, m2 = -3e38f;
#pragma unroll
  for (int j = 0; j < 4; ++j) {
    h16x8 a = ((const h16x8*)s1)[j * 64 + lane];
    h16x8 b = ((const h16x8*)s2)[j * 64 + lane];
#pragma unroll
    for (int q = 0; q < 8; ++q) {
      v1[j * 8 + q] = (float)a[q]; v2[j * 8 + q] = (float)b[q];
      m1 = fmaxf(m1, v1[j * 8 + q]); m2 = fmaxf(m2, v2[j * 8 + q]);
    }
  }
#pragma unroll
  for (int off = 1; off < 64; off <<= 1) {
    m1 = fmaxf(m1, __shfl_xor(m1, off));
    m2 = fmaxf(m2, __shfl_xor(m2, off));
  }
  float l1 = 0.f, l2 = 0.f;
#pragma unroll
  for (int e = 0; e < 32; ++e) {
    v1[e] = __expf(v1[e] - m1); l1 += v1[e];
    v2[e] = __expf(v2[e] - m2); l2 += v2[e];
  }
#pragma unroll
  for (int off = 1; off < 64; off <<= 1) {
    l1 += __shfl_xor(l1, off);
    l2 += __shfl_xor(l2, off);
  }
  const float r1 = 1.f / l1, r2 = lam / l2;
  _Float16* d = D + row * 2048;
#pragma unroll
  for (int j = 0; j < 4; ++j) {
    h16x8 h;
#pragma unroll
    for (int q = 0; q < 8; ++q)
      h[q] = (_Float16)(v1[j * 8 + q] * r1 - v2[j * 8 + q] * r2);
    ((h16x8*)d)[j * 64 + lane] = h;
  }
}

// ---------------------------------------------------------------------------
// one wave per row: out = O / sqrt(mean(O^2) + eps) * 0.2, f16 in, f32 out
__global__ __launch_bounds__(256) void rmsnorm(const _Float16* __restrict__ O,
                                               float* __restrict__ out) {
  const long row = (long)blockIdx.x * 4 + (threadIdx.x >> 6);
  const int lane = threadIdx.x & 63;
  const _Float16* o = O + row * 1024;
  h16x8 a = ((const h16x8*)o)[lane];
  h16x8 b = ((const h16x8*)o)[64 + lane];
  float xa[8], xb[8];
  float ss = 0.f;
#pragma unroll
  for (int q = 0; q < 8; ++q) {
    xa[q] = (float)a[q]; xb[q] = (float)b[q];
    ss += xa[q] * xa[q] + xb[q] * xb[q];
  }
#pragma unroll
  for (int off = 1; off < 64; off <<= 1) ss += __shfl_xor(ss, off);
  const float s = 0.2f * rsqrtf(ss * (1.f / 1024.f) + 1e-5f);
  float* po = out + row * 1024;
  f32x4 r;
#pragma unroll
  for (int q = 0; q < 4; ++q) r[q] = xa[q] * s;
  *(f32x4*)(po + lane * 8) = r;
#pragma unroll
  for (int q = 0; q < 4; ++q) r[q] = xa[4 + q] * s;
  *(f32x4*)(po + lane * 8 + 4) = r;
#pragma unroll
  for (int q = 0; q < 4; ++q) r[q] = xb[q] * s;
  *(f32x4*)(po + 512 + lane * 8) = r;
#pragma unroll
  for (int q = 0; q < 4; ++q) r[q] = xb[4 + q] * s;
  *(f32x4*)(po + 512 + lane * 8 + 4) = r;
}

// ---------------------------------------------------------------------------
extern "C" void kernel_launch(void* const* d_in, const int* in_sizes, int n_in,
                              void* d_out, int out_size, void* d_ws, size_t ws_size,
                              hipStream_t stream) {
  const float* x   = (const float*)d_in[0];
  const float* wq  = (const float*)d_in[1];
  const float* wk  = (const float*)d_in[2];
  const float* wv  = (const float*)d_in[3];
  const float* lq1 = (const float*)d_in[4];
  const float* lk1 = (const float*)d_in[5];
  const float* lq2 = (const float*)d_in[6];
  const float* lk2 = (const float*)d_in[7];
  float* out = (float*)d_out;

  const size_t MB = 1ull << 20;
  char* ws = (char*)d_ws;
  _Float16* xh   = (_Float16*)(ws + 0);          // 16MB  8192x1024
  _Float16* Wp   = (_Float16*)(ws + 16 * MB);    // 10MB  5120x1024 [q|k|v], B^T
  _Float16* qkv  = (_Float16*)(ws + 26 * MB);    // 80MB  8192x5120
  _Float16* vt   = (_Float16*)(ws + 106 * MB);   // 16MB  4 x 1024x2048
  _Float16* S1   = (_Float16*)(ws + 122 * MB);   // 32MB  4 x 2048x2048
  _Float16* S2   = (_Float16*)(ws + 154 * MB);   // 32MB
  float*    lam  = (float*)(ws + 186 * MB);      // 4B
  _Float16* diff = (_Float16*)(ws + 26 * MB);    // 32MB, reuses dead qkv
  _Float16* opre = (_Float16*)(ws + 58 * MB);    // 16MB, reuses dead qkv

  const float scale = 0.17677669529663689f;  // 1024^-0.25

  cast_x<<<4096, 256, 0, stream>>>(x, xh);
  tcw<<<dim3(32, 16), 256, 0, stream>>>(wq, Wp, 1024, 2048, scale);
  tcw<<<dim3(32, 16), 256, 0, stream>>>(wk, Wp + 2048l * 1024, 1024, 2048, 1.0f);
  tcw<<<dim3(16, 16), 256, 0, stream>>>(wv, Wp + 4096l * 1024, 1024, 1024, 1.0f);
  lambda_k<<<1, 1024, 0, stream>>>(lq1, lk1, lq2, lk2, lam);

  // fused projection: qkv = xh @ Wp^T  (8192 x 5120, K=1024)
  gemm256<4, _Float16><<<640, 512, 0, stream>>>(xh, Wp, qkv, 1024, 1024, 1024, 5120,
                                                0, 0, 0, 20, 32);

  // v region (cols 4096..5119) -> vt (b,1024,2048)
  trans16<<<dim3(16, 32, 4), 256, 0, stream>>>(qkv + 4096, vt, 2048, 5120,
                                               2048l * 5120, 1024l * 2048);

  // S_p = q_p @ k_p^T (scale folded into q), f16 out
  gemm256<4, _Float16><<<256, 512, 0, stream>>>(qkv, qkv + 2048, S1, 1024, 5120, 5120, 2048,
                                                2048l * 5120, 2048l * 5120, 2048l * 2048, 8, 8);
  gemm256<4, _Float16><<<256, 512, 0, stream>>>(qkv + 1024, qkv + 3072, S2, 1024, 5120, 5120, 2048,
                                                2048l * 5120, 2048l * 5120, 2048l * 2048, 8, 8);

  softmax_diff<<<2048, 256, 0, stream>>>(S1, S2, diff, lam);

  // opre = diff @ vt^T  (K = 2048), BN=128 -> 256 blocks exact fill
  gemm256<2, _Float16><<<256, 512, 0, stream>>>(diff, vt, opre, 2048, 2048, 2048, 1024,
                                                2048l * 2048, 1024l * 2048, 2048l * 1024, 8, 8);

  rmsnorm<<<2048, 256, 0, stream>>>(opre, out);
}

// Round 3
// 339.623 us; speedup vs baseline: 1.0155x; 1.0155x over previous
//
#include <hip/hip_runtime.h>

typedef float f32x4 __attribute__((ext_vector_type(4)));
typedef _Float16 h16x8 __attribute__((ext_vector_type(8)));
typedef _Float16 h16x4 __attribute__((ext_vector_type(4)));

#define GLOAD_LDS16(gp, lp) __builtin_amdgcn_global_load_lds(               \
    (const __attribute__((address_space(1))) void*)(gp),                    \
    (__attribute__((address_space(3))) void*)(lp), 16, 0, 0)

// ---------------------------------------------------------------------------
// cast x (f32) -> f16, 8 elems/thread
__global__ __launch_bounds__(256) void cast_x(const float* __restrict__ x,
                                              _Float16* __restrict__ xh) {
  long i = (long)blockIdx.x * 256 + threadIdx.x;  // 8-elem groups
  f32x4 a = *(const f32x4*)(x + i * 8);
  f32x4 b = *(const f32x4*)(x + i * 8 + 4);
  h16x8 h;
  h[0] = (_Float16)a[0]; h[1] = (_Float16)a[1];
  h[2] = (_Float16)a[2]; h[3] = (_Float16)a[3];
  h[4] = (_Float16)b[0]; h[5] = (_Float16)b[1];
  h[6] = (_Float16)b[2]; h[7] = (_Float16)b[3];
  *(h16x8*)(xh + i * 8) = h;
}

// ---------------------------------------------------------------------------
// transpose + cast weight: in f32 (K x N) row-major -> out f16 (N x K), *scale
__global__ __launch_bounds__(256) void tcw(const float* __restrict__ in,
                                           _Float16* __restrict__ out,
                                           int Kd, int Nd, float scale) {
  __shared__ float tile[64][65];
  const int t = threadIdx.x;
  const int k0 = blockIdx.y * 64, n0 = blockIdx.x * 64;
  const int tr = t >> 4, tc = (t & 15) * 4;
#pragma unroll
  for (int i = 0; i < 4; ++i) {
    int r = i * 16 + tr;
    f32x4 a = *(const f32x4*)(in + (long)(k0 + r) * Nd + n0 + tc);
    tile[r][tc + 0] = a[0]; tile[r][tc + 1] = a[1];
    tile[r][tc + 2] = a[2]; tile[r][tc + 3] = a[3];
  }
  __syncthreads();
#pragma unroll
  for (int i = 0; i < 4; ++i) {
    int r = i * 16 + tr;  // n index
    h16x4 h;
#pragma unroll
    for (int q = 0; q < 4; ++q) h[q] = (_Float16)(tile[tc + q][r] * scale);
    *(h16x4*)(out + (long)(n0 + r) * Kd + k0 + tc) = h;
  }
}

// ---------------------------------------------------------------------------
// f16 tile transpose: in (R x C, ld=Cd) -> out (C x R, ld=R), batched
__global__ __launch_bounds__(256) void trans16(const _Float16* __restrict__ in,
                                               _Float16* __restrict__ out,
                                               int R, int Cd, long ibatch, long obatch) {
  __shared__ _Float16 tile[64][72];
  in += (long)blockIdx.z * ibatch;
  out += (long)blockIdx.z * obatch;
  const int t = threadIdx.x;
  const int r0 = blockIdx.y * 64, c0 = blockIdx.x * 64;
  const int tr = t >> 3, tc8 = (t & 7) * 8;
#pragma unroll
  for (int i = 0; i < 2; ++i) {
    int r = i * 32 + tr;
    h16x8 a = *(const h16x8*)(in + (long)(r0 + r) * Cd + c0 + tc8);
    *(h16x8*)(&tile[r][tc8]) = a;
  }
  __syncthreads();
#pragma unroll
  for (int i = 0; i < 2; ++i) {
    int r = i * 32 + tr;  // c index
    h16x8 h;
#pragma unroll
    for (int q = 0; q < 8; ++q) h[q] = tile[tc8 + q][r];
    *(h16x8*)(out + (long)(c0 + r) * R + r0 + tc8) = h;
  }
}

// ---------------------------------------------------------------------------
// lambda_full = exp(sum lq1*lk1) - exp(sum lq2*lk2) + 0.8
__global__ __launch_bounds__(1024) void lambda_k(const float* __restrict__ lq1,
                                                 const float* __restrict__ lk1,
                                                 const float* __restrict__ lq2,
                                                 const float* __restrict__ lk2,
                                                 float* __restrict__ lam) {
  __shared__ float sh1[16], sh2[16];
  const int t = threadIdx.x;
  float p1 = lq1[t] * lk1[t];
  float p2 = lq2[t] * lk2[t];
#pragma unroll
  for (int off = 1; off < 64; off <<= 1) {
    p1 += __shfl_xor(p1, off);
    p2 += __shfl_xor(p2, off);
  }
  if ((t & 63) == 0) { sh1[t >> 6] = p1; sh2[t >> 6] = p2; }
  __syncthreads();
  if (t == 0) {
    float s1 = 0.f, s2 = 0.f;
    for (int i = 0; i < 16; ++i) { s1 += sh1[i]; s2 += sh2[i]; }
    lam[0] = __expf(s1) - __expf(s2) + 0.8f;
  }
}

// ---------------------------------------------------------------------------
// C(M x N) = A(M x K) @ B(N x K)^T. BM=256, BN=NREP*64, BK=32, 8 waves
// (2M x 4N), ring-of-4 LDS sub-buffers (depth-3 prefetch), counted vmcnt
// (never 0 mid-loop), ONE s_barrier per K-step, swizzled LDS (2-way max),
// setprio around MFMA, bijective XCD remap.
// Swizzle: LDS slot s' of row r holds global k-slice gs = (s' - (r>>1)) & 3;
// reader at (r, lg) uses slot (lg + (r>>1)) & 3. Chunk%8 covers each residue
// exactly 2x per 16-lane group -> conflict-free (2-way is free, m136).
template <int NREP, typename CT>
__global__ __launch_bounds__(512, 2) void gemmp(
    const _Float16* __restrict__ A, const _Float16* __restrict__ B,
    CT* __restrict__ C, int K, int lda, int ldb, int ldc,
    long abatch, long bbatch, long cbatch, int nbx, int nby) {
  constexpr int BN = NREP * 64;
  constexpr int L = 2 + NREP / 2;  // global_load_lds per thread per sub-tile
  __shared__ _Float16 As[4][256 * 32];
  __shared__ _Float16 Bs[4][BN * 32];

  // bijective XCD-aware remap (m204); grids here are multiples of 8
  const int nwg = gridDim.x;
  const int orig = blockIdx.x;
  const int qd = nwg >> 3, rm = nwg & 7;
  const int xcd = orig & 7, sub = orig >> 3;
  const int wgid = (xcd < rm ? xcd * (qd + 1) : rm * (qd + 1) + (xcd - rm) * qd) + sub;

  const int bz = wgid / (nbx * nby);
  const int rem = wgid - bz * nbx * nby;
  const int by = rem / nbx;
  const int bx = rem - by * nbx;

  const int t = threadIdx.x;
  const int lane = t & 63, wv = t >> 6;
  const int wm = wv >> 2, wn = wv & 3;
  const int lg = lane >> 4, l15 = lane & 15;

  const _Float16* Ab = A + (long)bz * abatch + (long)(by * 256) * lda;
  const _Float16* Bb = B + (long)bz * bbatch + (long)(bx * BN) * ldb;

  // stage sub-tile S (k-offset S*32) into ring slot S&3, swizzled source
  auto stage = [&](int S) {
    const int rg = S & 3;
    const int kof = S * 32;
#pragma unroll
    for (int j = 0; j < 2; ++j) {
      int e = t + j * 512;              // A chunk 0..1023
      int r = e >> 2, sp = e & 3;
      int gs = (sp - (r >> 1)) & 3;
      GLOAD_LDS16(Ab + (long)r * lda + kof + gs * 8, &As[rg][e * 8]);
    }
#pragma unroll
    for (int j = 0; j < NREP / 2; ++j) {
      int e = t + j * 512;              // B chunk 0..BN*4-1
      int r = e >> 2, sp = e & 3;
      int gs = (sp - (r >> 1)) & 3;
      GLOAD_LDS16(Bb + (long)r * ldb + kof + gs * 8, &Bs[rg][e * 8]);
    }
  };

  f32x4 acc[8][NREP] = {};
  const int NS = K >> 5;  // requires K >= 96

  stage(0); stage(1); stage(2);

  for (int S = 0; S < NS; ++S) {
    // drain sub-tile S only; keep S+1, S+2 in flight (counted vmcnt, T4)
    if (S + 1 >= NS) {
      asm volatile("s_waitcnt vmcnt(0)" ::: "memory");
    } else if (S + 2 >= NS) {
      if constexpr (NREP == 4) asm volatile("s_waitcnt vmcnt(4)" ::: "memory");
      else                     asm volatile("s_waitcnt vmcnt(3)" ::: "memory");
    } else {
      if constexpr (NREP == 4) asm volatile("s_waitcnt vmcnt(8)" ::: "memory");
      else                     asm volatile("s_waitcnt vmcnt(6)" ::: "memory");
    }
    __builtin_amdgcn_s_barrier();
    asm volatile("" ::: "memory");

    if (S + 3 < NS) stage(S + 3);  // slot (S-1)&3, freed by the barrier above

    const int rg = S & 3;
    const _Float16* Asb = &As[rg][0];
    const _Float16* Bsb = &Bs[rg][0];
    h16x8 af[8], bf[NREP];
#pragma unroll
    for (int m = 0; m < 8; ++m) {
      int r = wm * 128 + m * 16 + l15;
      int ch = r * 4 + ((lg + (r >> 1)) & 3);
      af[m] = *(const h16x8*)(Asb + ch * 8);
    }
#pragma unroll
    for (int n = 0; n < NREP; ++n) {
      int r = wn * (NREP * 16) + n * 16 + l15;
      int ch = r * 4 + ((lg + (r >> 1)) & 3);
      bf[n] = *(const h16x8*)(Bsb + ch * 8);
    }
    __builtin_amdgcn_s_setprio(1);
#pragma unroll
    for (int m = 0; m < 8; ++m)
#pragma unroll
      for (int n = 0; n < NREP; ++n)
        acc[m][n] = __builtin_amdgcn_mfma_f32_16x16x32_f16(af[m], bf[n], acc[m][n], 0, 0, 0);
    __builtin_amdgcn_s_setprio(0);
  }

  CT* Cb = C + (long)bz * cbatch;
  const int crow0 = by * 256 + wm * 128;
  const int ccol0 = bx * BN + wn * (NREP * 16);
#pragma unroll
  for (int m = 0; m < 8; ++m)
#pragma unroll
    for (int n = 0; n < NREP; ++n)
#pragma unroll
      for (int j = 0; j < 4; ++j)
        Cb[(long)(crow0 + m * 16 + lg * 4 + j) * ldc + ccol0 + n * 16 + l15] =
            (CT)acc[m][n][j];
}

// ---------------------------------------------------------------------------
// one wave per row: diff = softmax(S1) - lam * softmax(S2), f16 in/out
__global__ __launch_bounds__(256) void softmax_diff(const _Float16* __restrict__ S1,
                                                    const _Float16* __restrict__ S2,
                                                    _Float16* __restrict__ D,
                                                    const float* __restrict__ lamp) {
  const long row = (long)blockIdx.x * 4 + (threadIdx.x >> 6);
  const int lane = threadIdx.x & 63;
  const float lam = *lamp;
  const _Float16* s1 = S1 + row * 2048;
  const _Float16* s2 = S2 + row * 2048;
  float v1[32], v2[32];
  float m1 = -3e38f, m2 = -3e38f;
#pragma unroll
  for (int j = 0; j < 4; ++j) {
    h16x8 a = ((const h16x8*)s1)[j * 64 + lane];
    h16x8 b = ((const h16x8*)s2)[j * 64 + lane];
#pragma unroll
    for (int q = 0; q < 8; ++q) {
      v1[j * 8 + q] = (float)a[q]; v2[j * 8 + q] = (float)b[q];
      m1 = fmaxf(m1, v1[j * 8 + q]); m2 = fmaxf(m2, v2[j * 8 + q]);
    }
  }
#pragma unroll
  for (int off = 1; off < 64; off <<= 1) {
    m1 = fmaxf(m1, __shfl_xor(m1, off));
    m2 = fmaxf(m2, __shfl_xor(m2, off));
  }
  float l1 = 0.f, l2 = 0.f;
#pragma unroll
  for (int e = 0; e < 32; ++e) {
    v1[e] = __expf(v1[e] - m1); l1 += v1[e];
    v2[e] = __expf(v2[e] - m2); l2 += v2[e];
  }
#pragma unroll
  for (int off = 1; off < 64; off <<= 1) {
    l1 += __shfl_xor(l1, off);
    l2 += __shfl_xor(l2, off);
  }
  const float r1 = 1.f / l1, r2 = lam / l2;
  _Float16* d = D + row * 2048;
#pragma unroll
  for (int j = 0; j < 4; ++j) {
    h16x8 h;
#pragma unroll
    for (int q = 0; q < 8; ++q)
      h[q] = (_Float16)(v1[j * 8 + q] * r1 - v2[j * 8 + q] * r2);
    ((h16x8*)d)[j * 64 + lane] = h;
  }
}

// ---------------------------------------------------------------------------
// one wave per row: out = O / sqrt(mean(O^2) + eps) * 0.2, f16 in, f32 out
__global__ __launch_bounds__(256) void rmsnorm(const _Float16* __restrict__ O,
                                               float* __restrict__ out) {
  const long row = (long)blockIdx.x * 4 + (threadIdx.x >> 6);
  const int lane = threadIdx.x & 63;
  const _Float16* o = O + row * 1024;
  h16x8 a = ((const h16x8*)o)[lane];
  h16x8 b = ((const h16x8*)o)[64 + lane];
  float xa[8], xb[8];
  float ss = 0.f;
#pragma unroll
  for (int q = 0; q < 8; ++q) {
    xa[q] = (float)a[q]; xb[q] = (float)b[q];
    ss += xa[q] * xa[q] + xb[q] * xb[q];
  }
#pragma unroll
  for (int off = 1; off < 64; off <<= 1) ss += __shfl_xor(ss, off);
  const float s = 0.2f * rsqrtf(ss * (1.f / 1024.f) + 1e-5f);
  float* po = out + row * 1024;
  f32x4 r;
#pragma unroll
  for (int q = 0; q < 4; ++q) r[q] = xa[q] * s;
  *(f32x4*)(po + lane * 8) = r;
#pragma unroll
  for (int q = 0; q < 4; ++q) r[q] = xa[4 + q] * s;
  *(f32x4*)(po + lane * 8 + 4) = r;
#pragma unroll
  for (int q = 0; q < 4; ++q) r[q] = xb[q] * s;
  *(f32x4*)(po + 512 + lane * 8) = r;
#pragma unroll
  for (int q = 0; q < 4; ++q) r[q] = xb[4 + q] * s;
  *(f32x4*)(po + 512 + lane * 8 + 4) = r;
}

// ---------------------------------------------------------------------------
extern "C" void kernel_launch(void* const* d_in, const int* in_sizes, int n_in,
                              void* d_out, int out_size, void* d_ws, size_t ws_size,
                              hipStream_t stream) {
  const float* x   = (const float*)d_in[0];
  const float* wq  = (const float*)d_in[1];
  const float* wk  = (const float*)d_in[2];
  const float* wv  = (const float*)d_in[3];
  const float* lq1 = (const float*)d_in[4];
  const float* lk1 = (const float*)d_in[5];
  const float* lq2 = (const float*)d_in[6];
  const float* lk2 = (const float*)d_in[7];
  float* out = (float*)d_out;

  const size_t MB = 1ull << 20;
  char* ws = (char*)d_ws;
  _Float16* xh   = (_Float16*)(ws + 0);          // 16MB  8192x1024
  _Float16* Wp   = (_Float16*)(ws + 16 * MB);    // 10MB  5120x1024 [q|k|v], B^T
  _Float16* qkv  = (_Float16*)(ws + 26 * MB);    // 80MB  8192x5120
  _Float16* vt   = (_Float16*)(ws + 106 * MB);   // 16MB  4 x 1024x2048
  _Float16* S1   = (_Float16*)(ws + 122 * MB);   // 32MB  4 x 2048x2048
  _Float16* S2   = (_Float16*)(ws + 154 * MB);   // 32MB
  float*    lam  = (float*)(ws + 186 * MB);      // 4B
  _Float16* diff = (_Float16*)(ws + 26 * MB);    // 32MB, reuses dead qkv
  _Float16* opre = (_Float16*)(ws + 58 * MB);    // 16MB, reuses dead qkv

  const float scale = 0.17677669529663689f;  // 1024^-0.25

  cast_x<<<4096, 256, 0, stream>>>(x, xh);
  tcw<<<dim3(32, 16), 256, 0, stream>>>(wq, Wp, 1024, 2048, scale);
  tcw<<<dim3(32, 16), 256, 0, stream>>>(wk, Wp + 2048l * 1024, 1024, 2048, 1.0f);
  tcw<<<dim3(16, 16), 256, 0, stream>>>(wv, Wp + 4096l * 1024, 1024, 1024, 1.0f);
  lambda_k<<<1, 1024, 0, stream>>>(lq1, lk1, lq2, lk2, lam);

  // fused projection: qkv = xh @ Wp^T  (8192 x 5120, K=1024)
  gemmp<4, _Float16><<<640, 512, 0, stream>>>(xh, Wp, qkv, 1024, 1024, 1024, 5120,
                                              0, 0, 0, 20, 32);

  // v region (cols 4096..5119) -> vt (b,1024,2048)
  trans16<<<dim3(16, 32, 4), 256, 0, stream>>>(qkv + 4096, vt, 2048, 5120,
                                               2048l * 5120, 1024l * 2048);

  // S_p = q_p @ k_p^T (scale folded into q), f16 out
  gemmp<4, _Float16><<<256, 512, 0, stream>>>(qkv, qkv + 2048, S1, 1024, 5120, 5120, 2048,
                                              2048l * 5120, 2048l * 5120, 2048l * 2048, 8, 8);
  gemmp<4, _Float16><<<256, 512, 0, stream>>>(qkv + 1024, qkv + 3072, S2, 1024, 5120, 5120, 2048,
                                              2048l * 5120, 2048l * 5120, 2048l * 2048, 8, 8);

  softmax_diff<<<2048, 256, 0, stream>>>(S1, S2, diff, lam);

  // opre = diff @ vt^T  (K = 2048), BN=128 -> 256 blocks exact fill
  gemmp<2, _Float16><<<256, 512, 0, stream>>>(diff, vt, opre, 2048, 2048, 2048, 1024,
                                              2048l * 2048, 1024l * 2048, 2048l * 1024, 8, 8);

  rmsnorm<<<2048, 256, 0, stream>>>(opre, out);
}

// Round 4
// 296.457 us; speedup vs baseline: 1.1634x; 1.1456x over previous
//
#include <hip/hip_runtime.h>

typedef float f32x4 __attribute__((ext_vector_type(4)));
typedef _Float16 h16x8 __attribute__((ext_vector_type(8)));
typedef _Float16 h16x4 __attribute__((ext_vector_type(4)));

#define GLOAD_LDS16(gp, lp) __builtin_amdgcn_global_load_lds(               \
    (const __attribute__((address_space(1))) void*)(gp),                    \
    (__attribute__((address_space(3))) void*)(lp), 16, 0, 0)

// ---------------------------------------------------------------------------
// cast x (f32) -> f16, 8 elems/thread
__global__ __launch_bounds__(256) void cast_x(const float* __restrict__ x,
                                              _Float16* __restrict__ xh) {
  long i = (long)blockIdx.x * 256 + threadIdx.x;  // 8-elem groups
  f32x4 a = *(const f32x4*)(x + i * 8);
  f32x4 b = *(const f32x4*)(x + i * 8 + 4);
  h16x8 h;
  h[0] = (_Float16)a[0]; h[1] = (_Float16)a[1];
  h[2] = (_Float16)a[2]; h[3] = (_Float16)a[3];
  h[4] = (_Float16)b[0]; h[5] = (_Float16)b[1];
  h[6] = (_Float16)b[2]; h[7] = (_Float16)b[3];
  *(h16x8*)(xh + i * 8) = h;
}

// ---------------------------------------------------------------------------
// transpose + cast weight: in f32 (K x N) row-major -> out f16 (N x K), *scale
__global__ __launch_bounds__(256) void tcw(const float* __restrict__ in,
                                           _Float16* __restrict__ out,
                                           int Kd, int Nd, float scale) {
  __shared__ float tile[64][65];
  const int t = threadIdx.x;
  const int k0 = blockIdx.y * 64, n0 = blockIdx.x * 64;
  const int tr = t >> 4, tc = (t & 15) * 4;
#pragma unroll
  for (int i = 0; i < 4; ++i) {
    int r = i * 16 + tr;
    f32x4 a = *(const f32x4*)(in + (long)(k0 + r) * Nd + n0 + tc);
    tile[r][tc + 0] = a[0]; tile[r][tc + 1] = a[1];
    tile[r][tc + 2] = a[2]; tile[r][tc + 3] = a[3];
  }
  __syncthreads();
#pragma unroll
  for (int i = 0; i < 4; ++i) {
    int r = i * 16 + tr;  // n index
    h16x4 h;
#pragma unroll
    for (int q = 0; q < 4; ++q) h[q] = (_Float16)(tile[tc + q][r] * scale);
    *(h16x4*)(out + (long)(n0 + r) * Kd + k0 + tc) = h;
  }
}

// ---------------------------------------------------------------------------
// f16 tile transpose: in (R x C, ld=Cd) -> out (C x R, ld=R), batched
__global__ __launch_bounds__(256) void trans16(const _Float16* __restrict__ in,
                                               _Float16* __restrict__ out,
                                               int R, int Cd, long ibatch, long obatch) {
  __shared__ _Float16 tile[64][72];
  in += (long)blockIdx.z * ibatch;
  out += (long)blockIdx.z * obatch;
  const int t = threadIdx.x;
  const int r0 = blockIdx.y * 64, c0 = blockIdx.x * 64;
  const int tr = t >> 3, tc8 = (t & 7) * 8;
#pragma unroll
  for (int i = 0; i < 2; ++i) {
    int r = i * 32 + tr;
    h16x8 a = *(const h16x8*)(in + (long)(r0 + r) * Cd + c0 + tc8);
    *(h16x8*)(&tile[r][tc8]) = a;
  }
  __syncthreads();
#pragma unroll
  for (int i = 0; i < 2; ++i) {
    int r = i * 32 + tr;  // c index
    h16x8 h;
#pragma unroll
    for (int q = 0; q < 8; ++q) h[q] = tile[tc8 + q][r];
    *(h16x8*)(out + (long)(c0 + r) * R + r0 + tc8) = h;
  }
}

// ---------------------------------------------------------------------------
// lambda_full = exp(sum lq1*lk1) - exp(sum lq2*lk2) + 0.8
__global__ __launch_bounds__(1024) void lambda_k(const float* __restrict__ lq1,
                                                 const float* __restrict__ lk1,
                                                 const float* __restrict__ lq2,
                                                 const float* __restrict__ lk2,
                                                 float* __restrict__ lam) {
  __shared__ float sh1[16], sh2[16];
  const int t = threadIdx.x;
  float p1 = lq1[t] * lk1[t];
  float p2 = lq2[t] * lk2[t];
#pragma unroll
  for (int off = 1; off < 64; off <<= 1) {
    p1 += __shfl_xor(p1, off);
    p2 += __shfl_xor(p2, off);
  }
  if ((t & 63) == 0) { sh1[t >> 6] = p1; sh2[t >> 6] = p2; }
  __syncthreads();
  if (t == 0) {
    float s1 = 0.f, s2 = 0.f;
    for (int i = 0; i < 16; ++i) { s1 += sh1[i]; s2 += sh2[i]; }
    lam[0] = __expf(s1) - __expf(s2) + 0.8f;
  }
}

// ---------------------------------------------------------------------------
// C(M x N) = A(M x K) @ B(N x K)^T. BM=256, BN=NREP*64, BK=32, 8 waves
// (2M x 4N), ring-of-4 LDS, PHASED K-step (T3+T4): per step 2 phases of
// {ds_read subtile; stage issue; [vmcnt] barrier; lgkmcnt(0); 16 MFMA;
// barrier}. Counted vmcnt, graduated tail, never drain mid-loop. Swizzled
// LDS (conflict-free, verified R3). setprio around MFMA (T5). XCD remap.
// Requires: M%256==0, N%BN==0, K%32==0, K>=96.
template <int NREP, typename CT>
__global__ __launch_bounds__(512, 2) void gemmp(
    const _Float16* __restrict__ A, const _Float16* __restrict__ B,
    CT* __restrict__ C, int K, int lda, int ldb, int ldc,
    long abatch, long bbatch, long cbatch, int nbx, int nby) {
  constexpr int BN = NREP * 64;
  __shared__ _Float16 As[4][256 * 32];
  __shared__ _Float16 Bs[4][BN * 32];

  // bijective XCD-aware remap (m204)
  const int nwg = gridDim.x;
  const int orig = blockIdx.x;
  const int qd = nwg >> 3, rm = nwg & 7;
  const int xcd = orig & 7, sub = orig >> 3;
  const int wgid = (xcd < rm ? xcd * (qd + 1) : rm * (qd + 1) + (xcd - rm) * qd) + sub;

  const int bz = wgid / (nbx * nby);
  const int rem = wgid - bz * nbx * nby;
  const int by = rem / nbx;
  const int bx = rem - by * nbx;

  const int t = threadIdx.x;
  const int lane = t & 63, wv = t >> 6;
  const int wm = wv >> 2, wn = wv & 3;
  const int lg = lane >> 4, l15 = lane & 15;

  const _Float16* Ab = A + (long)bz * abatch + (long)(by * 256) * lda;
  const _Float16* Bb = B + (long)bz * bbatch + (long)(bx * BN) * ldb;

  // --- staging source/dest offsets (swizzle: slot sp holds gs=(sp-(r>>1))&3)
  const int eA0 = t,       rA0 = eA0 >> 2, sA0 = ((eA0 & 3) - (rA0 >> 1)) & 3;
  const int eA1 = t + 512, rA1 = eA1 >> 2, sA1 = ((eA1 & 3) - (rA1 >> 1)) & 3;
  const long goA0 = (long)rA0 * lda + sA0 * 8;
  const long goA1 = (long)rA1 * lda + sA1 * 8;
  const int eB0 = t,       rB0 = eB0 >> 2, sB0 = ((eB0 & 3) - (rB0 >> 1)) & 3;
  const long goB0 = (long)rB0 * ldb + sB0 * 8;
  const int eB1 = t + 512, rB1 = eB1 >> 2, sB1 = ((eB1 & 3) - (rB1 >> 1)) & 3;
  const long goB1 = (long)rB1 * ldb + sB1 * 8;

  auto stA0 = [&](int S) { GLOAD_LDS16(Ab + goA0 + S * 32, &As[S & 3][eA0 * 8]); };
  auto stA1 = [&](int S) { GLOAD_LDS16(Ab + goA1 + S * 32, &As[S & 3][eA1 * 8]); };
  auto stB0 = [&](int S) { GLOAD_LDS16(Bb + goB0 + S * 32, &Bs[S & 3][eB0 * 8]); };
  auto stB1 = [&](int S) { GLOAD_LDS16(Bb + goB1 + S * 32, &Bs[S & 3][eB1 * 8]); };

  // --- reader offsets (f16 units within a ring slot)
  int offA[8], offB[NREP];
#pragma unroll
  for (int m = 0; m < 8; ++m) {
    int r = wm * 128 + m * 16 + l15;
    offA[m] = (r * 4 + ((lg + (r >> 1)) & 3)) * 8;
  }
#pragma unroll
  for (int n = 0; n < NREP; ++n) {
    int r = wn * (NREP * 16) + n * 16 + l15;
    offB[n] = (r * 4 + ((lg + (r >> 1)) & 3)) * 8;
  }

  f32x4 acc[8][NREP] = {};
  const int NS = K >> 5;

  // prologue: stage slots 0,1,2 fully; ensure slot 0 landed everywhere
  for (int P = 0; P < 3; ++P) {
    stA0(P); stA1(P); stB0(P);
    if constexpr (NREP == 4) stB1(P);
  }
  if constexpr (NREP == 4) asm volatile("s_waitcnt vmcnt(8)" ::: "memory");
  else                     asm volatile("s_waitcnt vmcnt(6)" ::: "memory");
  __builtin_amdgcn_s_barrier();

  for (int S = 0; S < NS; ++S) {
    const int rg = S & 3;
    const _Float16* Asb = &As[rg][0];
    const _Float16* Bsb = &Bs[rg][0];
    const bool pf = (S + 3 < NS);
    h16x8 af[4], bf[NREP];

    // ================= phase 1: A-half0 x all B =================
#pragma unroll
    for (int m = 0; m < 4; ++m) af[m] = *(const h16x8*)(Asb + offA[m]);
#pragma unroll
    for (int n = 0; n < NREP; ++n) bf[n] = *(const h16x8*)(Bsb + offB[n]);
    if (pf) { stA0(S + 3); stA1(S + 3); }
    __builtin_amdgcn_s_barrier();
    asm volatile("s_waitcnt lgkmcnt(0)" ::: "memory");
    __builtin_amdgcn_sched_barrier(0);
    __builtin_amdgcn_s_setprio(1);
#pragma unroll
    for (int m = 0; m < 4; ++m)
#pragma unroll
      for (int n = 0; n < NREP; ++n)
        acc[m][n] = __builtin_amdgcn_mfma_f32_16x16x32_f16(af[m], bf[n], acc[m][n], 0, 0, 0);
    __builtin_amdgcn_s_setprio(0);
    __builtin_amdgcn_sched_barrier(0);
    __builtin_amdgcn_s_barrier();

    // ================= phase 2: A-half1 x all B =================
#pragma unroll
    for (int m = 0; m < 4; ++m) af[m] = *(const h16x8*)(Asb + offA[4 + m]);
    if (pf) {
      stB0(S + 3);
      if constexpr (NREP == 4) stB1(S + 3);
    }
    // counted vmcnt: force slot S+1 landed; keep S+2 (+S+3) in flight
    {
      const int newer = NS - S - 2;  // steps staged beyond S+1
      if constexpr (NREP == 4) {
        if (newer >= 2)      asm volatile("s_waitcnt vmcnt(8)" ::: "memory");
        else if (newer == 1) asm volatile("s_waitcnt vmcnt(4)" ::: "memory");
        else                 asm volatile("s_waitcnt vmcnt(0)" ::: "memory");
      } else {
        if (newer >= 2)      asm volatile("s_waitcnt vmcnt(6)" ::: "memory");
        else if (newer == 1) asm volatile("s_waitcnt vmcnt(3)" ::: "memory");
        else                 asm volatile("s_waitcnt vmcnt(0)" ::: "memory");
      }
    }
    __builtin_amdgcn_s_barrier();
    asm volatile("s_waitcnt lgkmcnt(0)" ::: "memory");
    __builtin_amdgcn_sched_barrier(0);
    __builtin_amdgcn_s_setprio(1);
#pragma unroll
    for (int m = 0; m < 4; ++m)
#pragma unroll
      for (int n = 0; n < NREP; ++n)
        acc[4 + m][n] = __builtin_amdgcn_mfma_f32_16x16x32_f16(af[m], bf[n], acc[4 + m][n], 0, 0, 0);
    __builtin_amdgcn_s_setprio(0);
    __builtin_amdgcn_sched_barrier(0);
    __builtin_amdgcn_s_barrier();
  }

  CT* Cb = C + (long)bz * cbatch;
  const int crow0 = by * 256 + wm * 128;
  const int ccol0 = bx * BN + wn * (NREP * 16);
#pragma unroll
  for (int m = 0; m < 8; ++m)
#pragma unroll
    for (int n = 0; n < NREP; ++n)
#pragma unroll
      for (int j = 0; j < 4; ++j)
        Cb[(long)(crow0 + m * 16 + lg * 4 + j) * ldc + ccol0 + n * 16 + l15] =
            (CT)acc[m][n][j];
}

// ---------------------------------------------------------------------------
// one wave per row: diff = softmax(S1) - lam * softmax(S2), f16 in/out
__global__ __launch_bounds__(256) void softmax_diff(const _Float16* __restrict__ S1,
                                                    const _Float16* __restrict__ S2,
                                                    _Float16* __restrict__ D,
                                                    const float* __restrict__ lamp) {
  const long row = (long)blockIdx.x * 4 + (threadIdx.x >> 6);
  const int lane = threadIdx.x & 63;
  const float lam = *lamp;
  const _Float16* s1 = S1 + row * 2048;
  const _Float16* s2 = S2 + row * 2048;
  float v1[32], v2[32];
  float m1 = -3e38f, m2 = -3e38f;
#pragma unroll
  for (int j = 0; j < 4; ++j) {
    h16x8 a = ((const h16x8*)s1)[j * 64 + lane];
    h16x8 b = ((const h16x8*)s2)[j * 64 + lane];
#pragma unroll
    for (int q = 0; q < 8; ++q) {
      v1[j * 8 + q] = (float)a[q]; v2[j * 8 + q] = (float)b[q];
      m1 = fmaxf(m1, v1[j * 8 + q]); m2 = fmaxf(m2, v2[j * 8 + q]);
    }
  }
#pragma unroll
  for (int off = 1; off < 64; off <<= 1) {
    m1 = fmaxf(m1, __shfl_xor(m1, off));
    m2 = fmaxf(m2, __shfl_xor(m2, off));
  }
  float l1 = 0.f, l2 = 0.f;
#pragma unroll
  for (int e = 0; e < 32; ++e) {
    v1[e] = __expf(v1[e] - m1); l1 += v1[e];
    v2[e] = __expf(v2[e] - m2); l2 += v2[e];
  }
#pragma unroll
  for (int off = 1; off < 64; off <<= 1) {
    l1 += __shfl_xor(l1, off);
    l2 += __shfl_xor(l2, off);
  }
  const float r1 = 1.f / l1, r2 = lam / l2;
  _Float16* d = D + row * 2048;
#pragma unroll
  for (int j = 0; j < 4; ++j) {
    h16x8 h;
#pragma unroll
    for (int q = 0; q < 8; ++q)
      h[q] = (_Float16)(v1[j * 8 + q] * r1 - v2[j * 8 + q] * r2);
    ((h16x8*)d)[j * 64 + lane] = h;
  }
}

// ---------------------------------------------------------------------------
// one wave per row: out = O / sqrt(mean(O^2) + eps) * 0.2, f16 in, f32 out
__global__ __launch_bounds__(256) void rmsnorm(const _Float16* __restrict__ O,
                                               float* __restrict__ out) {
  const long row = (long)blockIdx.x * 4 + (threadIdx.x >> 6);
  const int lane = threadIdx.x & 63;
  const _Float16* o = O + row * 1024;
  h16x8 a = ((const h16x8*)o)[lane];
  h16x8 b = ((const h16x8*)o)[64 + lane];
  float xa[8], xb[8];
  float ss = 0.f;
#pragma unroll
  for (int q = 0; q < 8; ++q) {
    xa[q] = (float)a[q]; xb[q] = (float)b[q];
    ss += xa[q] * xa[q] + xb[q] * xb[q];
  }
#pragma unroll
  for (int off = 1; off < 64; off <<= 1) ss += __shfl_xor(ss, off);
  const float s = 0.2f * rsqrtf(ss * (1.f / 1024.f) + 1e-5f);
  float* po = out + row * 1024;
  f32x4 r;
#pragma unroll
  for (int q = 0; q < 4; ++q) r[q] = xa[q] * s;
  *(f32x4*)(po + lane * 8) = r;
#pragma unroll
  for (int q = 0; q < 4; ++q) r[q] = xa[4 + q] * s;
  *(f32x4*)(po + lane * 8 + 4) = r;
#pragma unroll
  for (int q = 0; q < 4; ++q) r[q] = xb[q] * s;
  *(f32x4*)(po + 512 + lane * 8) = r;
#pragma unroll
  for (int q = 0; q < 4; ++q) r[q] = xb[4 + q] * s;
  *(f32x4*)(po + 512 + lane * 8 + 4) = r;
}

// ---------------------------------------------------------------------------
extern "C" void kernel_launch(void* const* d_in, const int* in_sizes, int n_in,
                              void* d_out, int out_size, void* d_ws, size_t ws_size,
                              hipStream_t stream) {
  const float* x   = (const float*)d_in[0];
  const float* wq  = (const float*)d_in[1];
  const float* wk  = (const float*)d_in[2];
  const float* wv  = (const float*)d_in[3];
  const float* lq1 = (const float*)d_in[4];
  const float* lk1 = (const float*)d_in[5];
  const float* lq2 = (const float*)d_in[6];
  const float* lk2 = (const float*)d_in[7];
  float* out = (float*)d_out;

  const size_t MB = 1ull << 20;
  char* ws = (char*)d_ws;
  _Float16* xh   = (_Float16*)(ws + 0);          // 16MB  8192x1024
  _Float16* Wp   = (_Float16*)(ws + 16 * MB);    // 10MB  5120x1024 [q|k|v], B^T
  _Float16* qkv  = (_Float16*)(ws + 26 * MB);    // 80MB  8192x5120
  _Float16* vt   = (_Float16*)(ws + 106 * MB);   // 16MB  4 x 1024x2048
  _Float16* S1   = (_Float16*)(ws + 122 * MB);   // 32MB  4 x 2048x2048
  _Float16* S2   = (_Float16*)(ws + 154 * MB);   // 32MB
  float*    lam  = (float*)(ws + 186 * MB);      // 4B
  _Float16* diff = (_Float16*)(ws + 26 * MB);    // 32MB, reuses dead qkv
  _Float16* opre = (_Float16*)(ws + 58 * MB);    // 16MB, reuses dead qkv

  const float scale = 0.17677669529663689f;  // 1024^-0.25

  cast_x<<<4096, 256, 0, stream>>>(x, xh);
  tcw<<<dim3(32, 16), 256, 0, stream>>>(wq, Wp, 1024, 2048, scale);
  tcw<<<dim3(32, 16), 256, 0, stream>>>(wk, Wp + 2048l * 1024, 1024, 2048, 1.0f);
  tcw<<<dim3(16, 16), 256, 0, stream>>>(wv, Wp + 4096l * 1024, 1024, 1024, 1.0f);
  lambda_k<<<1, 1024, 0, stream>>>(lq1, lk1, lq2, lk2, lam);

  // fused projection: qkv = xh @ Wp^T  (8192 x 5120, K=1024)
  gemmp<4, _Float16><<<640, 512, 0, stream>>>(xh, Wp, qkv, 1024, 1024, 1024, 5120,
                                              0, 0, 0, 20, 32);

  // v region (cols 4096..5119) -> vt (b,1024,2048)
  trans16<<<dim3(16, 32, 4), 256, 0, stream>>>(qkv + 4096, vt, 2048, 5120,
                                               2048l * 5120, 1024l * 2048);

  // S_p = q_p @ k_p^T (scale folded into q), f16 out
  gemmp<4, _Float16><<<256, 512, 0, stream>>>(qkv, qkv + 2048, S1, 1024, 5120, 5120, 2048,
                                              2048l * 5120, 2048l * 5120, 2048l * 2048, 8, 8);
  gemmp<4, _Float16><<<256, 512, 0, stream>>>(qkv + 1024, qkv + 3072, S2, 1024, 5120, 5120, 2048,
                                              2048l * 5120, 2048l * 5120, 2048l * 2048, 8, 8);

  softmax_diff<<<2048, 256, 0, stream>>>(S1, S2, diff, lam);

  // opre = diff @ vt^T  (K = 2048), NREP=2 -> BN=128, 256 blocks exact fill
  gemmp<2, _Float16><<<256, 512, 0, stream>>>(diff, vt, opre, 2048, 2048, 2048, 1024,
                                              2048l * 2048, 1024l * 2048, 2048l * 1024, 8, 8);

  rmsnorm<<<2048, 256, 0, stream>>>(opre, out);
}

// Round 5
// 292.585 us; speedup vs baseline: 1.1788x; 1.0132x over previous
//
#include <hip/hip_runtime.h>

typedef float f32x4 __attribute__((ext_vector_type(4)));
typedef _Float16 h16x8 __attribute__((ext_vector_type(8)));
typedef _Float16 h16x4 __attribute__((ext_vector_type(4)));

#define GLOAD_LDS16(gp, lp) __builtin_amdgcn_global_load_lds(               \
    (const __attribute__((address_space(1))) void*)(gp),                    \
    (__attribute__((address_space(3))) void*)(lp), 16, 0, 0)

// ---------------------------------------------------------------------------
// cast x (f32) -> f16, 8 elems/thread
__global__ __launch_bounds__(256) void cast_x(const float* __restrict__ x,
                                              _Float16* __restrict__ xh) {
  long i = (long)blockIdx.x * 256 + threadIdx.x;  // 8-elem groups
  f32x4 a = *(const f32x4*)(x + i * 8);
  f32x4 b = *(const f32x4*)(x + i * 8 + 4);
  h16x8 h;
  h[0] = (_Float16)a[0]; h[1] = (_Float16)a[1];
  h[2] = (_Float16)a[2]; h[3] = (_Float16)a[3];
  h[4] = (_Float16)b[0]; h[5] = (_Float16)b[1];
  h[6] = (_Float16)b[2]; h[7] = (_Float16)b[3];
  *(h16x8*)(xh + i * 8) = h;
}

// ---------------------------------------------------------------------------
// transpose + cast weight: in f32 (K x N) row-major -> out f16 (N x K), *scale
__global__ __launch_bounds__(256) void tcw(const float* __restrict__ in,
                                           _Float16* __restrict__ out,
                                           int Kd, int Nd, float scale) {
  __shared__ float tile[64][65];
  const int t = threadIdx.x;
  const int k0 = blockIdx.y * 64, n0 = blockIdx.x * 64;
  const int tr = t >> 4, tc = (t & 15) * 4;
#pragma unroll
  for (int i = 0; i < 4; ++i) {
    int r = i * 16 + tr;
    f32x4 a = *(const f32x4*)(in + (long)(k0 + r) * Nd + n0 + tc);
    tile[r][tc + 0] = a[0]; tile[r][tc + 1] = a[1];
    tile[r][tc + 2] = a[2]; tile[r][tc + 3] = a[3];
  }
  __syncthreads();
#pragma unroll
  for (int i = 0; i < 4; ++i) {
    int r = i * 16 + tr;  // n index
    h16x4 h;
#pragma unroll
    for (int q = 0; q < 4; ++q) h[q] = (_Float16)(tile[tc + q][r] * scale);
    *(h16x4*)(out + (long)(n0 + r) * Kd + k0 + tc) = h;
  }
}

// ---------------------------------------------------------------------------
// f16 tile transpose: in (R x C, ld=Cd) -> out (C x R, ld=R), batched
__global__ __launch_bounds__(256) void trans16(const _Float16* __restrict__ in,
                                               _Float16* __restrict__ out,
                                               int R, int Cd, long ibatch, long obatch) {
  __shared__ _Float16 tile[64][72];
  in += (long)blockIdx.z * ibatch;
  out += (long)blockIdx.z * obatch;
  const int t = threadIdx.x;
  const int r0 = blockIdx.y * 64, c0 = blockIdx.x * 64;
  const int tr = t >> 3, tc8 = (t & 7) * 8;
#pragma unroll
  for (int i = 0; i < 2; ++i) {
    int r = i * 32 + tr;
    h16x8 a = *(const h16x8*)(in + (long)(r0 + r) * Cd + c0 + tc8);
    *(h16x8*)(&tile[r][tc8]) = a;
  }
  __syncthreads();
#pragma unroll
  for (int i = 0; i < 2; ++i) {
    int r = i * 32 + tr;  // c index
    h16x8 h;
#pragma unroll
    for (int q = 0; q < 8; ++q) h[q] = tile[tc8 + q][r];
    *(h16x8*)(out + (long)(c0 + r) * R + r0 + tc8) = h;
  }
}

// ---------------------------------------------------------------------------
// lambda_full = exp(sum lq1*lk1) - exp(sum lq2*lk2) + 0.8
__global__ __launch_bounds__(1024) void lambda_k(const float* __restrict__ lq1,
                                                 const float* __restrict__ lk1,
                                                 const float* __restrict__ lq2,
                                                 const float* __restrict__ lk2,
                                                 float* __restrict__ lam) {
  __shared__ float sh1[16], sh2[16];
  const int t = threadIdx.x;
  float p1 = lq1[t] * lk1[t];
  float p2 = lq2[t] * lk2[t];
#pragma unroll
  for (int off = 1; off < 64; off <<= 1) {
    p1 += __shfl_xor(p1, off);
    p2 += __shfl_xor(p2, off);
  }
  if ((t & 63) == 0) { sh1[t >> 6] = p1; sh2[t >> 6] = p2; }
  __syncthreads();
  if (t == 0) {
    float s1 = 0.f, s2 = 0.f;
    for (int i = 0; i < 16; ++i) { s1 += sh1[i]; s2 += sh2[i]; }
    lam[0] = __expf(s1) - __expf(s2) + 0.8f;
  }
}

// ---------------------------------------------------------------------------
// C(M x N) = A(M x K) @ B(N x K)^T. BM=256, BN=NREP*64, BK=32, 8 waves
// (2M x 4N), ring-of-4 LDS, 2 phases per K-step {ds_read subtile; stage;
// [vmcnt] barrier; MFMA cluster; barrier}. Counted vmcnt (T4, never drain
// mid-loop). UNPINNED: no asm lgkmcnt / sched_barrier — the compiler emits
// fine-grained lgkmcnt(N) per MFMA operand (m97 evidence; m141: pinning
// costs ~40%). Swizzled LDS (0 conflicts, verified R3). setprio (T5).
// Bijective XCD remap. Optional second batch axis (natt) with strides
// a2 (A and B) / c2 (C) for fusing S1+S2 into one dispatch.
// Requires: M%256==0, N%BN==0, K%32==0, K>=128.
template <int NREP, typename CT>
__global__ __launch_bounds__(512, 2) void gemmp(
    const _Float16* __restrict__ A, const _Float16* __restrict__ B,
    CT* __restrict__ C, int K, int lda, int ldb, int ldc,
    long abatch, long bbatch, long cbatch, long a2, long c2, int natt,
    int nbx, int nby) {
  constexpr int BN = NREP * 64;
  __shared__ _Float16 As[4][256 * 32];
  __shared__ _Float16 Bs[4][BN * 32];

  // bijective XCD-aware remap (m204)
  const int nwg = gridDim.x;
  const int orig = blockIdx.x;
  const int qd = nwg >> 3, rm = nwg & 7;
  const int xcd = orig & 7, sub = orig >> 3;
  const int wgid = (xcd < rm ? xcd * (qd + 1) : rm * (qd + 1) + (xcd - rm) * qd) + sub;

  const int z = wgid / (nbx * nby);
  const int rem = wgid - z * nbx * nby;
  const int by = rem / nbx;
  const int bx = rem - by * nbx;
  const int att = z % natt;
  const int bz = z / natt;

  const int t = threadIdx.x;
  const int lane = t & 63, wv = t >> 6;
  const int wm = wv >> 2, wn = wv & 3;
  const int lg = lane >> 4, l15 = lane & 15;

  const _Float16* Ab = A + (long)bz * abatch + (long)att * a2 + (long)(by * 256) * lda;
  const _Float16* Bb = B + (long)bz * bbatch + (long)att * a2 + (long)(bx * BN) * ldb;

  // --- staging source/dest offsets (swizzle: slot sp holds gs=(sp-(r>>1))&3)
  const int eA0 = t,       rA0 = eA0 >> 2, sA0 = ((eA0 & 3) - (rA0 >> 1)) & 3;
  const int eA1 = t + 512, rA1 = eA1 >> 2, sA1 = ((eA1 & 3) - (rA1 >> 1)) & 3;
  const long goA0 = (long)rA0 * lda + sA0 * 8;
  const long goA1 = (long)rA1 * lda + sA1 * 8;
  const int eB0 = t,       rB0 = eB0 >> 2, sB0 = ((eB0 & 3) - (rB0 >> 1)) & 3;
  const long goB0 = (long)rB0 * ldb + sB0 * 8;
  const int eB1 = t + 512, rB1 = eB1 >> 2, sB1 = ((eB1 & 3) - (rB1 >> 1)) & 3;
  const long goB1 = (long)rB1 * ldb + sB1 * 8;

  auto stA0 = [&](int S) { GLOAD_LDS16(Ab + goA0 + S * 32, &As[S & 3][eA0 * 8]); };
  auto stA1 = [&](int S) { GLOAD_LDS16(Ab + goA1 + S * 32, &As[S & 3][eA1 * 8]); };
  auto stB0 = [&](int S) { GLOAD_LDS16(Bb + goB0 + S * 32, &Bs[S & 3][eB0 * 8]); };
  auto stB1 = [&](int S) { GLOAD_LDS16(Bb + goB1 + S * 32, &Bs[S & 3][eB1 * 8]); };

  // --- reader offsets (f16 units within a ring slot)
  int offA[8], offB[NREP];
#pragma unroll
  for (int m = 0; m < 8; ++m) {
    int r = wm * 128 + m * 16 + l15;
    offA[m] = (r * 4 + ((lg + (r >> 1)) & 3)) * 8;
  }
#pragma unroll
  for (int n = 0; n < NREP; ++n) {
    int r = wn * (NREP * 16) + n * 16 + l15;
    offB[n] = (r * 4 + ((lg + (r >> 1)) & 3)) * 8;
  }

  f32x4 acc[8][NREP] = {};
  const int NS = K >> 5;

  // prologue: stage slots 0,1,2 fully; ensure slot 0 landed everywhere
  for (int P = 0; P < 3; ++P) {
    stA0(P); stA1(P); stB0(P);
    if constexpr (NREP == 4) stB1(P);
  }
  if constexpr (NREP == 4) asm volatile("s_waitcnt vmcnt(8)" ::: "memory");
  else                     asm volatile("s_waitcnt vmcnt(6)" ::: "memory");
  __builtin_amdgcn_s_barrier();

  for (int S = 0; S < NS; ++S) {
    const int rg = S & 3;
    const _Float16* Asb = &As[rg][0];
    const _Float16* Bsb = &Bs[rg][0];
    const bool pf = (S + 3 < NS);
    h16x8 af[4], bf[NREP];

    // ================= phase 1: A-half0 x all B =================
#pragma unroll
    for (int m = 0; m < 4; ++m) af[m] = *(const h16x8*)(Asb + offA[m]);
#pragma unroll
    for (int n = 0; n < NREP; ++n) bf[n] = *(const h16x8*)(Bsb + offB[n]);
    if (pf) { stA0(S + 3); stA1(S + 3); }
    __builtin_amdgcn_s_barrier();
    __builtin_amdgcn_s_setprio(1);
#pragma unroll
    for (int m = 0; m < 4; ++m)
#pragma unroll
      for (int n = 0; n < NREP; ++n)
        acc[m][n] = __builtin_amdgcn_mfma_f32_16x16x32_f16(af[m], bf[n], acc[m][n], 0, 0, 0);
    __builtin_amdgcn_s_setprio(0);
    __builtin_amdgcn_s_barrier();

    // ================= phase 2: A-half1 x all B =================
#pragma unroll
    for (int m = 0; m < 4; ++m) af[m] = *(const h16x8*)(Asb + offA[4 + m]);
    if (pf) {
      stB0(S + 3);
      if constexpr (NREP == 4) stB1(S + 3);
    }
    // counted vmcnt: force slot S+1 landed; keep S+2 (+S+3) in flight
    {
      const int newer = NS - S - 2;  // steps staged beyond S+1
      if constexpr (NREP == 4) {
        if (newer >= 2)      asm volatile("s_waitcnt vmcnt(8)" ::: "memory");
        else if (newer == 1) asm volatile("s_waitcnt vmcnt(4)" ::: "memory");
        else                 asm volatile("s_waitcnt vmcnt(0)" ::: "memory");
      } else {
        if (newer >= 2)      asm volatile("s_waitcnt vmcnt(6)" ::: "memory");
        else if (newer == 1) asm volatile("s_waitcnt vmcnt(3)" ::: "memory");
        else                 asm volatile("s_waitcnt vmcnt(0)" ::: "memory");
      }
    }
    __builtin_amdgcn_s_barrier();
    __builtin_amdgcn_s_setprio(1);
#pragma unroll
    for (int m = 0; m < 4; ++m)
#pragma unroll
      for (int n = 0; n < NREP; ++n)
        acc[4 + m][n] = __builtin_amdgcn_mfma_f32_16x16x32_f16(af[m], bf[n], acc[4 + m][n], 0, 0, 0);
    __builtin_amdgcn_s_setprio(0);
    __builtin_amdgcn_s_barrier();
  }

  CT* Cb = C + (long)bz * cbatch + (long)att * c2;
  const int crow0 = by * 256 + wm * 128;
  const int ccol0 = bx * BN + wn * (NREP * 16);
#pragma unroll
  for (int m = 0; m < 8; ++m)
#pragma unroll
    for (int n = 0; n < NREP; ++n)
#pragma unroll
      for (int j = 0; j < 4; ++j)
        Cb[(long)(crow0 + m * 16 + lg * 4 + j) * ldc + ccol0 + n * 16 + l15] =
            (CT)acc[m][n][j];
}

// ---------------------------------------------------------------------------
// one wave per row: diff = softmax(S1) - lam * softmax(S2), f16 in/out
__global__ __launch_bounds__(256) void softmax_diff(const _Float16* __restrict__ S1,
                                                    const _Float16* __restrict__ S2,
                                                    _Float16* __restrict__ D,
                                                    const float* __restrict__ lamp) {
  const long row = (long)blockIdx.x * 4 + (threadIdx.x >> 6);
  const int lane = threadIdx.x & 63;
  const float lam = *lamp;
  const _Float16* s1 = S1 + row * 2048;
  const _Float16* s2 = S2 + row * 2048;
  float v1[32], v2[32];
  float m1 = -3e38f, m2 = -3e38f;
#pragma unroll
  for (int j = 0; j < 4; ++j) {
    h16x8 a = ((const h16x8*)s1)[j * 64 + lane];
    h16x8 b = ((const h16x8*)s2)[j * 64 + lane];
#pragma unroll
    for (int q = 0; q < 8; ++q) {
      v1[j * 8 + q] = (float)a[q]; v2[j * 8 + q] = (float)b[q];
      m1 = fmaxf(m1, v1[j * 8 + q]); m2 = fmaxf(m2, v2[j * 8 + q]);
    }
  }
#pragma unroll
  for (int off = 1; off < 64; off <<= 1) {
    m1 = fmaxf(m1, __shfl_xor(m1, off));
    m2 = fmaxf(m2, __shfl_xor(m2, off));
  }
  float l1 = 0.f, l2 = 0.f;
#pragma unroll
  for (int e = 0; e < 32; ++e) {
    v1[e] = __expf(v1[e] - m1); l1 += v1[e];
    v2[e] = __expf(v2[e] - m2); l2 += v2[e];
  }
#pragma unroll
  for (int off = 1; off < 64; off <<= 1) {
    l1 += __shfl_xor(l1, off);
    l2 += __shfl_xor(l2, off);
  }
  const float r1 = 1.f / l1, r2 = lam / l2;
  _Float16* d = D + row * 2048;
#pragma unroll
  for (int j = 0; j < 4; ++j) {
    h16x8 h;
#pragma unroll
    for (int q = 0; q < 8; ++q)
      h[q] = (_Float16)(v1[j * 8 + q] * r1 - v2[j * 8 + q] * r2);
    ((h16x8*)d)[j * 64 + lane] = h;
  }
}

// ---------------------------------------------------------------------------
// one wave per row: out = O / sqrt(mean(O^2) + eps) * 0.2, f16 in, f32 out
__global__ __launch_bounds__(256) void rmsnorm(const _Float16* __restrict__ O,
                                               float* __restrict__ out) {
  const long row = (long)blockIdx.x * 4 + (threadIdx.x >> 6);
  const int lane = threadIdx.x & 63;
  const _Float16* o = O + row * 1024;
  h16x8 a = ((const h16x8*)o)[lane];
  h16x8 b = ((const h16x8*)o)[64 + lane];
  float xa[8], xb[8];
  float ss = 0.f;
#pragma unroll
  for (int q = 0; q < 8; ++q) {
    xa[q] = (float)a[q]; xb[q] = (float)b[q];
    ss += xa[q] * xa[q] + xb[q] * xb[q];
  }
#pragma unroll
  for (int off = 1; off < 64; off <<= 1) ss += __shfl_xor(ss, off);
  const float s = 0.2f * rsqrtf(ss * (1.f / 1024.f) + 1e-5f);
  float* po = out + row * 1024;
  f32x4 r;
#pragma unroll
  for (int q = 0; q < 4; ++q) r[q] = xa[q] * s;
  *(f32x4*)(po + lane * 8) = r;
#pragma unroll
  for (int q = 0; q < 4; ++q) r[q] = xa[4 + q] * s;
  *(f32x4*)(po + lane * 8 + 4) = r;
#pragma unroll
  for (int q = 0; q < 4; ++q) r[q] = xb[q] * s;
  *(f32x4*)(po + 512 + lane * 8) = r;
#pragma unroll
  for (int q = 0; q < 4; ++q) r[q] = xb[4 + q] * s;
  *(f32x4*)(po + 512 + lane * 8 + 4) = r;
}

// ---------------------------------------------------------------------------
extern "C" void kernel_launch(void* const* d_in, const int* in_sizes, int n_in,
                              void* d_out, int out_size, void* d_ws, size_t ws_size,
                              hipStream_t stream) {
  const float* x   = (const float*)d_in[0];
  const float* wq  = (const float*)d_in[1];
  const float* wk  = (const float*)d_in[2];
  const float* wv  = (const float*)d_in[3];
  const float* lq1 = (const float*)d_in[4];
  const float* lk1 = (const float*)d_in[5];
  const float* lq2 = (const float*)d_in[6];
  const float* lk2 = (const float*)d_in[7];
  float* out = (float*)d_out;

  const size_t MB = 1ull << 20;
  char* ws = (char*)d_ws;
  _Float16* xh   = (_Float16*)(ws + 0);          // 16MB  8192x1024
  _Float16* Wp   = (_Float16*)(ws + 16 * MB);    // 10MB  5120x1024 [q|k|v], B^T
  _Float16* qkv  = (_Float16*)(ws + 26 * MB);    // 80MB  8192x5120
  _Float16* vt   = (_Float16*)(ws + 106 * MB);   // 16MB  4 x 1024x2048
  _Float16* S1   = (_Float16*)(ws + 122 * MB);   // 32MB  4 x 2048x2048
  _Float16* S2   = (_Float16*)(ws + 154 * MB);   // 32MB
  float*    lam  = (float*)(ws + 186 * MB);      // 4B
  _Float16* diff = (_Float16*)(ws + 26 * MB);    // 32MB, reuses dead qkv
  _Float16* opre = (_Float16*)(ws + 58 * MB);    // 16MB, reuses dead qkv

  const float scale = 0.17677669529663689f;  // 1024^-0.25

  cast_x<<<4096, 256, 0, stream>>>(x, xh);
  tcw<<<dim3(32, 16), 256, 0, stream>>>(wq, Wp, 1024, 2048, scale);
  tcw<<<dim3(32, 16), 256, 0, stream>>>(wk, Wp + 2048l * 1024, 1024, 2048, 1.0f);
  tcw<<<dim3(16, 16), 256, 0, stream>>>(wv, Wp + 4096l * 1024, 1024, 1024, 1.0f);
  lambda_k<<<1, 1024, 0, stream>>>(lq1, lk1, lq2, lk2, lam);

  // fused projection: qkv = xh @ Wp^T  (8192 x 5120, K=1024)
  gemmp<4, _Float16><<<640, 512, 0, stream>>>(xh, Wp, qkv, 1024, 1024, 1024, 5120,
                                              0, 0, 0, 0, 0, 1, 20, 32);

  // v region (cols 4096..5119) -> vt (b,1024,2048)
  trans16<<<dim3(16, 32, 4), 256, 0, stream>>>(qkv + 4096, vt, 2048, 5120,
                                               2048l * 5120, 1024l * 2048);

  // S1 and S2 fused in one dispatch (natt=2): S_p = q_p @ k_p^T, f16 out
  gemmp<4, _Float16><<<512, 512, 0, stream>>>(qkv, qkv + 2048, S1, 1024, 5120, 5120, 2048,
                                              2048l * 5120, 2048l * 5120, 2048l * 2048,
                                              1024, 16777216l, 2, 8, 8);

  softmax_diff<<<2048, 256, 0, stream>>>(S1, S2, diff, lam);

  // opre = diff @ vt^T  (K = 2048), NREP=2 -> BN=128, 256 blocks exact fill
  gemmp<2, _Float16><<<256, 512, 0, stream>>>(diff, vt, opre, 2048, 2048, 2048, 1024,
                                              2048l * 2048, 1024l * 2048, 2048l * 1024,
                                              0, 0, 1, 8, 8);

  rmsnorm<<<2048, 256, 0, stream>>>(opre, out);
}

// Round 6
// 281.436 us; speedup vs baseline: 1.2255x; 1.0396x over previous
//
#include <hip/hip_runtime.h>

typedef float f32x4 __attribute__((ext_vector_type(4)));
typedef _Float16 h16x8 __attribute__((ext_vector_type(8)));
typedef _Float16 h16x4 __attribute__((ext_vector_type(4)));

#define GLOAD_LDS16(gp, lp) __builtin_amdgcn_global_load_lds(               \
    (const __attribute__((address_space(1))) void*)(gp),                    \
    (__attribute__((address_space(3))) void*)(lp), 16, 0, 0)

#define BARX do { __builtin_amdgcn_s_barrier(); asm volatile("" ::: "memory"); } while (0)
#define VMW(N) asm volatile("s_waitcnt vmcnt(" #N ")" ::: "memory")

// ---------------------------------------------------------------------------
// cast x (f32) -> f16, 8 elems/thread
__global__ __launch_bounds__(256) void cast_x(const float* __restrict__ x,
                                              _Float16* __restrict__ xh) {
  long i = (long)blockIdx.x * 256 + threadIdx.x;
  f32x4 a = *(const f32x4*)(x + i * 8);
  f32x4 b = *(const f32x4*)(x + i * 8 + 4);
  h16x8 h;
  h[0] = (_Float16)a[0]; h[1] = (_Float16)a[1];
  h[2] = (_Float16)a[2]; h[3] = (_Float16)a[3];
  h[4] = (_Float16)b[0]; h[5] = (_Float16)b[1];
  h[6] = (_Float16)b[2]; h[7] = (_Float16)b[3];
  *(h16x8*)(xh + i * 8) = h;
}

// ---------------------------------------------------------------------------
// transpose + cast weight: in f32 (K x N) row-major -> out f16 (N x K), *scale
__global__ __launch_bounds__(256) void tcw(const float* __restrict__ in,
                                           _Float16* __restrict__ out,
                                           int Kd, int Nd, float scale) {
  __shared__ float tile[64][65];
  const int t = threadIdx.x;
  const int k0 = blockIdx.y * 64, n0 = blockIdx.x * 64;
  const int tr = t >> 4, tc = (t & 15) * 4;
#pragma unroll
  for (int i = 0; i < 4; ++i) {
    int r = i * 16 + tr;
    f32x4 a = *(const f32x4*)(in + (long)(k0 + r) * Nd + n0 + tc);
    tile[r][tc + 0] = a[0]; tile[r][tc + 1] = a[1];
    tile[r][tc + 2] = a[2]; tile[r][tc + 3] = a[3];
  }
  __syncthreads();
#pragma unroll
  for (int i = 0; i < 4; ++i) {
    int r = i * 16 + tr;
    h16x4 h;
#pragma unroll
    for (int q = 0; q < 4; ++q) h[q] = (_Float16)(tile[tc + q][r] * scale);
    *(h16x4*)(out + (long)(n0 + r) * Kd + k0 + tc) = h;
  }
}

// ---------------------------------------------------------------------------
// f16 tile transpose: in (R x C, ld=Cd) -> out (C x R, ld=R), batched
__global__ __launch_bounds__(256) void trans16(const _Float16* __restrict__ in,
                                               _Float16* __restrict__ out,
                                               int R, int Cd, long ibatch, long obatch) {
  __shared__ _Float16 tile[64][72];
  in += (long)blockIdx.z * ibatch;
  out += (long)blockIdx.z * obatch;
  const int t = threadIdx.x;
  const int r0 = blockIdx.y * 64, c0 = blockIdx.x * 64;
  const int tr = t >> 3, tc8 = (t & 7) * 8;
#pragma unroll
  for (int i = 0; i < 2; ++i) {
    int r = i * 32 + tr;
    h16x8 a = *(const h16x8*)(in + (long)(r0 + r) * Cd + c0 + tc8);
    *(h16x8*)(&tile[r][tc8]) = a;
  }
  __syncthreads();
#pragma unroll
  for (int i = 0; i < 2; ++i) {
    int r = i * 32 + tr;
    h16x8 h;
#pragma unroll
    for (int q = 0; q < 8; ++q) h[q] = tile[tc8 + q][r];
    *(h16x8*)(out + (long)(c0 + r) * R + r0 + tc8) = h;
  }
}

// ---------------------------------------------------------------------------
// lambda_full = exp(sum lq1*lk1) - exp(sum lq2*lk2) + 0.8
__global__ __launch_bounds__(1024) void lambda_k(const float* __restrict__ lq1,
                                                 const float* __restrict__ lk1,
                                                 const float* __restrict__ lq2,
                                                 const float* __restrict__ lk2,
                                                 float* __restrict__ lam) {
  __shared__ float sh1[16], sh2[16];
  const int t = threadIdx.x;
  float p1 = lq1[t] * lk1[t];
  float p2 = lq2[t] * lk2[t];
#pragma unroll
  for (int off = 1; off < 64; off <<= 1) {
    p1 += __shfl_xor(p1, off);
    p2 += __shfl_xor(p2, off);
  }
  if ((t & 63) == 0) { sh1[t >> 6] = p1; sh2[t >> 6] = p2; }
  __syncthreads();
  if (t == 0) {
    float s1 = 0.f, s2 = 0.f;
    for (int i = 0; i < 16; ++i) { s1 += sh1[i]; s2 += sh2[i]; }
    lam[0] = __expf(s1) - __expf(s2) + 0.8f;
  }
}

// ---------------------------------------------------------------------------
// C(M x N) = A(M x K) @ B(N x K)^T. 8-phase m201-style schedule:
// BM=256, BN=NREP*64, BK=64, 2 K-tiles per unrolled iteration, 8 waves
// (2M x 4N), per-wave C = 128 x (BN/4). LDS: As[2][2][128][64],
// Bs[2][2][BN/2][64] (dbuf x half). Gray-code quadrant walk per K-tile:
// Q(sub0,n0) Q(sub0,n1) Q(sub1,n1) Q(sub1,n0); each phase re-reads only the
// CHANGED operand half (8 A-reads or NREP B-reads). One half-tile staged per
// phase; FIFO-counted vmcnt (never 0 mid-loop; full ledger in comments at
// each site). XOR swizzle slot^(row&7) on 128B rows -> 2-way max (free).
// Requires: M%256==0, N%BN==0, K%128==0, K>=256.
template <int NREP, typename CT>
__global__ __launch_bounds__(512, 2) void gemm8p(
    const _Float16* __restrict__ A, const _Float16* __restrict__ B,
    CT* __restrict__ C, int K, int lda, int ldb, int ldc,
    long abatch, long bbatch, long cbatch, long a2, long c2, int natt,
    int nbx, int nby) {
  constexpr int BN = NREP * 64;
  constexpr int BHALF = BN / 2;        // B rows per half: 128 or 64
  constexpr int BHB = BHALF * 64 * 2;  // bytes per B half: 16384 or 8192
  constexpr int NH = NREP / 2;         // B frags per sub: 2 or 1
  __shared__ _Float16 As[2][2][128][64];
  __shared__ _Float16 Bs[2][2][BHALF][64];

  // bijective XCD-aware remap (m204)
  const int nwg = gridDim.x;
  const int orig = blockIdx.x;
  const int qd = nwg >> 3, rm = nwg & 7;
  const int xcd = orig & 7, sub_ = orig >> 3;
  const int wgid = (xcd < rm ? xcd * (qd + 1) : rm * (qd + 1) + (xcd - rm) * qd) + sub_;

  const int z = wgid / (nbx * nby);
  const int rem = wgid - z * nbx * nby;
  const int by = rem / nbx;
  const int bx = rem - by * nbx;
  const int att = z % natt;
  const int bz = z / natt;

  const int t = threadIdx.x;
  const int lane = t & 63, wv = t >> 6;
  const int wm = wv >> 2, wn = wv & 3;
  const int lg = lane >> 4, l15 = lane & 15;

  const _Float16* Ab = A + (long)bz * abatch + (long)att * a2 + (long)(by * 256) * lda;
  const _Float16* Bb = B + (long)bz * bbatch + (long)att * a2 + (long)(bx * BN) * ldb;

  // staging thread geometry: chunk c -> row c>>3, slot c&7; global k-slot
  // gs = slot ^ (row&7)  (involution; reader applies the same XOR)
  const int rS = t >> 3;
  const int gsS = (t & 7) ^ (rS & 7);
  char* AsBase = (char*)&As[0][0][0][0];
  char* BsBase = (char*)&Bs[0][0][0][0];

  // stage A half-row-block l (rows l*64..l*64+63) of BOTH A-halves, tile T
  auto stgA = [&](int T) {
    // l is encoded by caller via which of stgA0/stgA1 — use two lambdas below
  };
  auto stgA0 = [&](int T) {  // rows 0-63 of h0 and h1  ("A.l0s")
    const long ko = (long)T * 64 + gsS * 8;
    char* dst = AsBase + (T & 1) * 32768 + t * 16;
    GLOAD_LDS16(Ab + (long)rS * lda + ko, dst);
    GLOAD_LDS16(Ab + (long)(128 + rS) * lda + ko, dst + 16384);
  };
  auto stgA1 = [&](int T) {  // rows 64-127 of h0 and h1 ("A.l1s")
    const long ko = (long)T * 64 + gsS * 8;
    char* dst = AsBase + (T & 1) * 32768 + 8192 + t * 16;
    GLOAD_LDS16(Ab + (long)(64 + rS) * lda + ko, dst);
    GLOAD_LDS16(Ab + (long)(192 + rS) * lda + ko, dst + 16384);
  };
  auto stgB = [&](int T, int h) {  // full B half h of tile T
    const long ko = (long)T * 64 + gsS * 8;
    char* dst = BsBase + (T & 1) * (2 * BHB) + h * BHB + t * 16;
    if constexpr (NREP == 4) {
      GLOAD_LDS16(Bb + (long)(h * 128 + rS) * ldb + ko, dst);
      GLOAD_LDS16(Bb + (long)(h * 128 + 64 + rS) * ldb + ko, dst + 8192);
    } else {
      GLOAD_LDS16(Bb + (long)(h * 64 + rS) * ldb + ko, dst);
    }
  };

  // reader bases: slot' = (kk*4+lg) ^ (l15&7) = (kk^b2)*4 + (lg^(l15&3))
  const int b2 = (l15 >> 2) & 1;
  const int lowsw = (lg ^ (l15 & 3)) * 16 + l15 * 128;
  const char* pA0 = AsBase + wm * 16384 + lowsw + b2 * 64;        // kk=0
  const char* pA1 = AsBase + wm * 16384 + lowsw + (1 - b2) * 64;  // kk=1
  const char* pB0 = BsBase + (wn >> 1) * BHB + (wn & 1) * (BHALF / 2 * 128) + lowsw + b2 * 64;
  const char* pB1 = pB0 - b2 * 64 + (1 - b2) * 64;

  h16x8 a[4][2], bA[NH][2], bB[NH][2], bC[NH][2];
  f32x4 acc[8][NREP] = {};

  auto rdA = [&](int d, int sub) {
#pragma unroll
    for (int j = 0; j < 4; ++j) {
      a[j][0] = *(const h16x8*)(pA0 + d * 32768 + (sub * 4 + j) * 2048);
      a[j][1] = *(const h16x8*)(pA1 + d * 32768 + (sub * 4 + j) * 2048);
    }
  };
  auto rdB = [&](int d, int sub, h16x8 (&dst)[NH][2]) {
#pragma unroll
    for (int j = 0; j < NH; ++j) {
      dst[j][0] = *(const h16x8*)(pB0 + d * (2 * BHB) + (sub * NH + j) * 2048);
      dst[j][1] = *(const h16x8*)(pB1 + d * (2 * BHB) + (sub * NH + j) * 2048);
    }
  };
  auto QUAD = [&](int ms, int ns, h16x8 (&bS)[NH][2]) {
#pragma unroll
    for (int j = 0; j < 4; ++j)
#pragma unroll
      for (int n = 0; n < NH; ++n) {
        const int mi = ms * 4 + j, ni = ns * NH + n;
        acc[mi][ni] = __builtin_amdgcn_mfma_f32_16x16x32_f16(a[j][0], bS[n][0], acc[mi][ni], 0, 0, 0);
        acc[mi][ni] = __builtin_amdgcn_mfma_f32_16x16x32_f16(a[j][1], bS[n][1], acc[mi][ni], 0, 0, 0);
      }
  };
#define PQ(MS, NS, BS) do { __builtin_amdgcn_s_setprio(1); QUAD(MS, NS, BS); \
                            __builtin_amdgcn_s_setprio(0); } while (0)

  const int NT = K >> 6;  // even, >= 4

  // prologue: slots = B0(0) A0(0) B1(0) A1(0) B0(1) A0(1); retire slots 1-3
  stgB(0, 0); stgA0(0); stgB(0, 1); stgA1(0); stgB(1, 0); stgA0(1);
  if constexpr (NREP == 4) VMW(6); else VMW(5);
  BARX;
  rdB(0, 0, bA);  // B-sub0(tile0)

  for (int T = 0; T < NT - 2; T += 2) {
    // P1: A-sub0(T); stage B1(T+1). vmcnt: cover P2's B-sub1(T) [B1(T)@P5-]
    rdA(0, 0); stgB(T + 1, 1);
    if constexpr (NREP == 4) VMW(8); else VMW(6);
    BARX; PQ(0, 0, bA); BARX;
    // P2: B-sub1(T); stage A1(T+1). cover P3's A-sub1(T) [A1(T)@P6-]
    rdB(0, 1, bB); stgA1(T + 1);
    if constexpr (NREP == 4) VMW(8); else VMW(6);
    BARX; PQ(0, 1, bB); BARX;
    // P3: A-sub1(T); stage B0(T+2). cover P4's B-sub0(T+1) [B1(T+1)@P1]
    rdA(0, 1); stgB(T + 2, 0);
    if constexpr (NREP == 4) VMW(4); else VMW(3);
    BARX; PQ(1, 1, bB); BARX;
    // P4: B-sub0(T+1)->bC; stage A0(T+2). cover P5's A-sub0(T+1) [A0(T+1)@P8-]
    rdB(1, 0, bC); stgA0(T + 2);
    if constexpr (NREP == 4) VMW(8); else VMW(6);
    BARX; PQ(1, 0, bA); BARX;
    // P5: A-sub0(T+1); stage B1(T+2). cover P6's B-sub1(T+1) [B1(T+1)@P1]
    rdA(1, 0); stgB(T + 2, 1);
    if constexpr (NREP == 4) VMW(8); else VMW(6);
    BARX; PQ(0, 0, bC); BARX;
    // P6: B-sub1(T+1); stage A1(T+2). cover P7's A-sub1(T+1) [A1(T+1)@P2]
    rdB(1, 1, bB); stgA1(T + 2);
    if constexpr (NREP == 4) VMW(8); else VMW(6);
    BARX; PQ(0, 1, bB); BARX;
    // P7: A-sub1(T+1); stage B0(T+3). cover P8's B-sub0(T+2) [B1(T+2)@P5]
    rdA(1, 1); stgB(T + 3, 0);
    if constexpr (NREP == 4) VMW(4); else VMW(3);
    BARX; PQ(1, 1, bB); BARX;
    // P8: B-sub0(T+2)->bA; stage A0(T+3). cover next-P1's A-sub0(T+2) [A0@P4]
    rdB(0, 0, bA); stgA0(T + 3);
    if constexpr (NREP == 4) VMW(8); else VMW(6);
    BARX; PQ(1, 0, bC); BARX;
  }

  {
    // final iteration, T = NT-2: only B1(T+1), A1(T+1) remain to stage
    rdA(0, 0); stgB(NT - 1, 1);
    if constexpr (NREP == 4) VMW(8); else VMW(6);
    BARX; PQ(0, 0, bA); BARX;
    rdB(0, 1, bB); stgA1(NT - 1);
    if constexpr (NREP == 4) VMW(8); else VMW(6);
    BARX; PQ(0, 1, bB); BARX;
    rdA(0, 1);
    VMW(2);
    BARX; PQ(1, 1, bB); BARX;
    rdB(1, 0, bC);
    if constexpr (NREP == 4) VMW(4); else VMW(3);
    BARX; PQ(1, 0, bA); BARX;
    rdA(1, 0);
    VMW(2);
    BARX; PQ(0, 0, bC); BARX;
    rdB(1, 1, bB);
    VMW(0);
    BARX; PQ(0, 1, bB); BARX;
    rdA(1, 1);
    BARX; PQ(1, 1, bB); BARX;
    PQ(1, 0, bC);
  }
#undef PQ

  CT* Cb = C + (long)bz * cbatch + (long)att * c2;
  const int crow0 = by * 256 + wm * 128;
  const int ccol0 = bx * BN + wn * (NREP * 16);
#pragma unroll
  for (int m = 0; m < 8; ++m)
#pragma unroll
    for (int n = 0; n < NREP; ++n)
#pragma unroll
      for (int j = 0; j < 4; ++j)
        Cb[(long)(crow0 + m * 16 + lg * 4 + j) * ldc + ccol0 + n * 16 + l15] =
            (CT)acc[m][n][j];
}

// ---------------------------------------------------------------------------
// one wave per row: diff = softmax(S1) - lam * softmax(S2), f16 in/out
__global__ __launch_bounds__(256) void softmax_diff(const _Float16* __restrict__ S1,
                                                    const _Float16* __restrict__ S2,
                                                    _Float16* __restrict__ D,
                                                    const float* __restrict__ lamp) {
  const long row = (long)blockIdx.x * 4 + (threadIdx.x >> 6);
  const int lane = threadIdx.x & 63;
  const float lam = *lamp;
  const _Float16* s1 = S1 + row * 2048;
  const _Float16* s2 = S2 + row * 2048;
  float v1[32], v2[32];
  float m1 = -3e38f, m2 = -3e38f;
#pragma unroll
  for (int j = 0; j < 4; ++j) {
    h16x8 a = ((const h16x8*)s1)[j * 64 + lane];
    h16x8 b = ((const h16x8*)s2)[j * 64 + lane];
#pragma unroll
    for (int q = 0; q < 8; ++q) {
      v1[j * 8 + q] = (float)a[q]; v2[j * 8 + q] = (float)b[q];
      m1 = fmaxf(m1, v1[j * 8 + q]); m2 = fmaxf(m2, v2[j * 8 + q]);
    }
  }
#pragma unroll
  for (int off = 1; off < 64; off <<= 1) {
    m1 = fmaxf(m1, __shfl_xor(m1, off));
    m2 = fmaxf(m2, __shfl_xor(m2, off));
  }
  float l1 = 0.f, l2 = 0.f;
#pragma unroll
  for (int e = 0; e < 32; ++e) {
    v1[e] = __expf(v1[e] - m1); l1 += v1[e];
    v2[e] = __expf(v2[e] - m2); l2 += v2[e];
  }
#pragma unroll
  for (int off = 1; off < 64; off <<= 1) {
    l1 += __shfl_xor(l1, off);
    l2 += __shfl_xor(l2, off);
  }
  const float r1 = 1.f / l1, r2 = lam / l2;
  _Float16* d = D + row * 2048;
#pragma unroll
  for (int j = 0; j < 4; ++j) {
    h16x8 h;
#pragma unroll
    for (int q = 0; q < 8; ++q)
      h[q] = (_Float16)(v1[j * 8 + q] * r1 - v2[j * 8 + q] * r2);
    ((h16x8*)d)[j * 64 + lane] = h;
  }
}

// ---------------------------------------------------------------------------
// one wave per row: out = O / sqrt(mean(O^2) + eps) * 0.2, f16 in, f32 out
__global__ __launch_bounds__(256) void rmsnorm(const _Float16* __restrict__ O,
                                               float* __restrict__ out) {
  const long row = (long)blockIdx.x * 4 + (threadIdx.x >> 6);
  const int lane = threadIdx.x & 63;
  const _Float16* o = O + row * 1024;
  h16x8 a = ((const h16x8*)o)[lane];
  h16x8 b = ((const h16x8*)o)[64 + lane];
  float xa[8], xb[8];
  float ss = 0.f;
#pragma unroll
  for (int q = 0; q < 8; ++q) {
    xa[q] = (float)a[q]; xb[q] = (float)b[q];
    ss += xa[q] * xa[q] + xb[q] * xb[q];
  }
#pragma unroll
  for (int off = 1; off < 64; off <<= 1) ss += __shfl_xor(ss, off);
  const float s = 0.2f * rsqrtf(ss * (1.f / 1024.f) + 1e-5f);
  float* po = out + row * 1024;
  f32x4 r;
#pragma unroll
  for (int q = 0; q < 4; ++q) r[q] = xa[q] * s;
  *(f32x4*)(po + lane * 8) = r;
#pragma unroll
  for (int q = 0; q < 4; ++q) r[q] = xa[4 + q] * s;
  *(f32x4*)(po + lane * 8 + 4) = r;
#pragma unroll
  for (int q = 0; q < 4; ++q) r[q] = xb[q] * s;
  *(f32x4*)(po + 512 + lane * 8) = r;
#pragma unroll
  for (int q = 0; q < 4; ++q) r[q] = xb[4 + q] * s;
  *(f32x4*)(po + 512 + lane * 8 + 4) = r;
}

// ---------------------------------------------------------------------------
extern "C" void kernel_launch(void* const* d_in, const int* in_sizes, int n_in,
                              void* d_out, int out_size, void* d_ws, size_t ws_size,
                              hipStream_t stream) {
  const float* x   = (const float*)d_in[0];
  const float* wq  = (const float*)d_in[1];
  const float* wk  = (const float*)d_in[2];
  const float* wv  = (const float*)d_in[3];
  const float* lq1 = (const float*)d_in[4];
  const float* lk1 = (const float*)d_in[5];
  const float* lq2 = (const float*)d_in[6];
  const float* lk2 = (const float*)d_in[7];
  float* out = (float*)d_out;

  const size_t MB = 1ull << 20;
  char* ws = (char*)d_ws;
  _Float16* xh   = (_Float16*)(ws + 0);          // 16MB  8192x1024
  _Float16* Wp   = (_Float16*)(ws + 16 * MB);    // 10MB  5120x1024 [q|k|v], B^T
  _Float16* qkv  = (_Float16*)(ws + 26 * MB);    // 80MB  8192x5120
  _Float16* vt   = (_Float16*)(ws + 106 * MB);   // 16MB  4 x 1024x2048
  _Float16* S1   = (_Float16*)(ws + 122 * MB);   // 32MB  4 x 2048x2048
  _Float16* S2   = (_Float16*)(ws + 154 * MB);   // 32MB
  float*    lam  = (float*)(ws + 186 * MB);      // 4B
  _Float16* diff = (_Float16*)(ws + 26 * MB);    // 32MB, reuses dead qkv
  _Float16* opre = (_Float16*)(ws + 58 * MB);    // 16MB, reuses dead qkv

  const float scale = 0.17677669529663689f;  // 1024^-0.25

  cast_x<<<4096, 256, 0, stream>>>(x, xh);
  tcw<<<dim3(32, 16), 256, 0, stream>>>(wq, Wp, 1024, 2048, scale);
  tcw<<<dim3(32, 16), 256, 0, stream>>>(wk, Wp + 2048l * 1024, 1024, 2048, 1.0f);
  tcw<<<dim3(16, 16), 256, 0, stream>>>(wv, Wp + 4096l * 1024, 1024, 1024, 1.0f);
  lambda_k<<<1, 1024, 0, stream>>>(lq1, lk1, lq2, lk2, lam);

  // fused projection: qkv = xh @ Wp^T  (8192 x 5120, K=1024)
  gemm8p<4, _Float16><<<640, 512, 0, stream>>>(xh, Wp, qkv, 1024, 1024, 1024, 5120,
                                               0, 0, 0, 0, 0, 1, 20, 32);

  // v region (cols 4096..5119) -> vt (b,1024,2048)
  trans16<<<dim3(16, 32, 4), 256, 0, stream>>>(qkv + 4096, vt, 2048, 5120,
                                               2048l * 5120, 1024l * 2048);

  // S1 and S2 fused in one dispatch (natt=2): S_p = q_p @ k_p^T, f16 out
  gemm8p<4, _Float16><<<512, 512, 0, stream>>>(qkv, qkv + 2048, S1, 1024, 5120, 5120, 2048,
                                               2048l * 5120, 2048l * 5120, 2048l * 2048,
                                               1024, 16777216l, 2, 8, 8);

  softmax_diff<<<2048, 256, 0, stream>>>(S1, S2, diff, lam);

  // opre = diff @ vt^T  (K = 2048), NREP=2 -> BN=128, 256 blocks exact fill
  gemm8p<2, _Float16><<<256, 512, 0, stream>>>(diff, vt, opre, 2048, 2048, 2048, 1024,
                                               2048l * 2048, 1024l * 2048, 2048l * 1024,
                                               0, 0, 1, 8, 8);

  rmsnorm<<<2048, 256, 0, stream>>>(opre, out);
}